// Round 8
// baseline (538.829 us; speedup 1.0000x reference)
//
#include <hip/hip_runtime.h>
#include <math.h>

#define S_  5
#define B_  2
#define C_  128
#define N_  576
#define SB  10
#define NPAIR 40
#define C2  256
#define ZRSPLIT 2   // conv_zr SPLITK (R8): 2 planes of f32 partials instead of 4

typedef short v8s __attribute__((ext_vector_type(8)));
typedef float v4f __attribute__((ext_vector_type(4)));

#define GLOBAL_AS __attribute__((address_space(1)))
#define LDS_AS    __attribute__((address_space(3)))

__device__ __forceinline__ unsigned short f2bf(float f) {
    union { float f; unsigned u; } v; v.f = f;
    unsigned r = (v.u + 0x7FFF + ((v.u >> 16) & 1)) >> 16;
    return (unsigned short)r;
}
__device__ __forceinline__ float bf2f(unsigned short h) {
    union { unsigned u; float f; } v; v.u = ((unsigned)h) << 16;
    return v.f;
}

// ------------------------------------------------------------------ weight pack bodies
// Fragment-major A: [cgb][kk][ch][g][tap_l][c(4)][l15(16)][quad(4)][j(8)]
// NOTE (R8): this linear order is SPLITK-agnostic — (kk,ch) lexicographic at SPLITK=4
// equals (kk',ch') at SPLITK=2 with the same channel windows, so conv_zr can consume
// the same pack at SPLITK=2 unchanged.
__device__ __forceinline__ void packA5_body(int idx, const float* __restrict__ w,
                                            unsigned short* __restrict__ Apk, int M)
{
    if (idx >= M * 6400) return;
    int r = idx;
    int j = r & 7;      r >>= 3;
    int quad = r & 3;   r >>= 2;
    int l15 = r & 15;   r >>= 4;
    int c = r & 3;      r >>= 2;
    int tap_l = r % 5;  r /= 5;
    int g = r % 5;      r /= 5;
    int ch = r & 1;     r >>= 1;
    int kk = r & 3;     r >>= 2;
    int cgb = r;
    int co = cgb * 64 + c * 16 + l15;
    int ci = kk * 64 + ch * 32 + quad * 8 + j;
    int tap = g * 5 + tap_l;
    Apk[idx] = f2bf(w[((size_t)co * 256 + ci) * 25 + tap]);
}
__device__ __forceinline__ void packA3_body(int idx, const float* __restrict__ wf,
                                            const float* __restrict__ wh,
                                            const float* __restrict__ wl,
                                            unsigned short* __restrict__ Apk)
{
    if (idx >= 384 * 1152) return;
    int r = idx;
    int j = r & 7;      r >>= 3;
    int quad = r & 3;   r >>= 2;
    int l15 = r & 15;   r >>= 4;
    int c = r & 3;      r >>= 2;
    int tap_l = r % 3;  r /= 3;
    int g = r % 3;      r /= 3;
    int ch = r & 1;     r >>= 1;
    int kk = r & 1;     r >>= 1;
    int cgb = r;
    int co = cgb * 64 + c * 16 + l15;
    const float* w = (co < 128) ? wf : (co < 256) ? wh : wl;
    int cl = co & 127;
    int ci = kk * 64 + ch * 32 + quad * 8 + j;
    int tap = g * 3 + tap_l;
    Apk[idx] = f2bf(w[((size_t)cl * 128 + ci) * 9 + tap]);
}
__device__ __forceinline__ void packWc_body(int idx, const float* __restrict__ w,
                                            unsigned short* __restrict__ o)
{
    if (idx < 128 * 128) o[idx] = f2bf(w[idx]);
}
// Wg[co][i] -> WgT[i][co]  (coalesced g_kernel reads)
__device__ __forceinline__ void packWgT_body(int idx, const float* __restrict__ w,
                                             float* __restrict__ o)
{
    if (idx >= 128 * 1152) return;
    int co = idx & 127, i = idx >> 7;
    o[(size_t)i * 128 + co] = w[(size_t)co * 1152 + i];
}

// ---------------------------------------------- transpose-cast body (x at it=0, rhb)
__device__ __forceinline__ void tc_body(
    int px0, int img,
    const float* __restrict__ src, const float* __restrict__ zrp,
    const float* __restrict__ zrb,
    unsigned short* __restrict__ dst, unsigned short* __restrict__ vfd)
{
    const size_t PLANE = (size_t)SB * C2 * N_;
    __shared__ float tile[128][9];
    int t = threadIdx.x;
    #pragma unroll
    for (int i = 0; i < 4; ++i) {
        int e = i * 256 + t; int ci = e >> 3; int px = e & 7;
        float v = src[((size_t)img * 128 + ci) * 576 + px0 + px];
        if (zrp) {
            size_t zi = ((size_t)img * C2 + 128 + ci) * 576 + px0 + px;
            float a = zrb[128 + ci];
            #pragma unroll
            for (int k = 0; k < ZRSPLIT; ++k) a += zrp[k * PLANE + zi];
            v *= 1.f / (1.f + __expf(-a));
        }
        tile[ci][px] = v;
        if (vfd) {
            int m = px0 + px;
            int ctile = ci >> 4, l15v = ci & 15;
            int sIdx = m >> 5, quadv = (m >> 3) & 3, j = m & 7;
            vfd[(((size_t)img * 8 + ctile) * 18 + sIdx) * 512 + (quadv * 16 + l15v) * 8 + j] = f2bf(v);
        }
    }
    __syncthreads();
    #pragma unroll
    for (int i = 0; i < 4; ++i) {
        int e = i * 256 + t; int pxl = e >> 7; int ci = e & 127;
        dst[((size_t)img * 576 + px0 + pxl) * 128 + ci] = f2bf(tile[ci][pxl]);
    }
}

// loop-phase tc (rhb path) stays a standalone kernel
__global__ __launch_bounds__(256) void tc_kernel(
    const float* __restrict__ src, const float* __restrict__ zrp,
    const float* __restrict__ zrb,
    unsigned short* __restrict__ dst, unsigned short* __restrict__ vfd)
{
    tc_body(blockIdx.x * 8, blockIdx.y, src, zrp, zrb, dst, vfd);
}

// ----------------------------------------- merged setup: all packs + initial tc
// pack bodies: 4 elements/thread (1024/block) — 4x MLP per thread, 1/4 the blocks
#define NB_A3   432
#define NB_A5ZR 1600
#define NB_A5H  800
#define NB_WC   16
#define NB_WGT  144
#define NB_TC   720
__global__ __launch_bounds__(256) void pack_all_kernel(
    const float* __restrict__ Wf_w, const float* __restrict__ Wh_w,
    const float* __restrict__ Wl_w, unsigned short* __restrict__ Wp3,
    const float* __restrict__ zr_w, unsigned short* __restrict__ Wpzr,
    const float* __restrict__ gh_w, unsigned short* __restrict__ Wph,
    const float* __restrict__ Wc,  unsigned short* __restrict__ Wcb,
    const float* __restrict__ Wg_w, float* __restrict__ WgT,
    const float* __restrict__ x, unsigned short* __restrict__ hT16,
    unsigned short* __restrict__ VFi)
{
    int bid = blockIdx.x, t = threadIdx.x;
    if (bid < NB_A3) {
        int base = bid * 1024 + t;
        #pragma unroll
        for (int k = 0; k < 4; ++k) packA3_body(base + k * 256, Wf_w, Wh_w, Wl_w, Wp3);
    } else if (bid < NB_A3 + NB_A5ZR) {
        int base = (bid - NB_A3) * 1024 + t;
        #pragma unroll
        for (int k = 0; k < 4; ++k) packA5_body(base + k * 256, zr_w, Wpzr, 256);
    } else if (bid < NB_A3 + NB_A5ZR + NB_A5H) {
        int base = (bid - NB_A3 - NB_A5ZR) * 1024 + t;
        #pragma unroll
        for (int k = 0; k < 4; ++k) packA5_body(base + k * 256, gh_w, Wph, 128);
    } else if (bid < NB_A3 + NB_A5ZR + NB_A5H + NB_WC) {
        int base = (bid - NB_A3 - NB_A5ZR - NB_A5H) * 1024 + t;
        #pragma unroll
        for (int k = 0; k < 4; ++k) packWc_body(base + k * 256, Wc, Wcb);
    } else if (bid < NB_A3 + NB_A5ZR + NB_A5H + NB_WC + NB_WGT) {
        int base = (bid - NB_A3 - NB_A5ZR - NB_A5H - NB_WC) * 1024 + t;
        #pragma unroll
        for (int k = 0; k < 4; ++k) packWgT_body(base + k * 256, Wg_w, WgT);
    } else {
        int b2 = bid - (NB_A3 + NB_A5ZR + NB_A5H + NB_WC + NB_WGT);
        tc_body((b2 % 72) * 8, b2 / 72, x, nullptr, nullptr, hT16, VFi);
    }
}

// ------------------------------------------------------ MFMA implicit-GEMM conv v7 (R3)
// MODE 0: f32 partial planes per kk (5x5 convs)
// MODE 1: conv3 full-K fused epilogue: +bias, write ftT(Q) / KFa(K-pack) / VFa(V-pack)
// Grid-capacity note: LDS 61.4KB -> 2 blocks/CU -> 512-block round capacity.
// R8: conv_zr SPLITK=2 (240 blocks, 1/CU, 20 subs) — same per-CU LDS cycles as
// SPLITK=4 (480 blocks, 2/CU, 10 subs) but HALF the f32 partial-plane traffic.
// conv_h stays SPLITK=4 (dropping it would leave half the CUs idle).
template<int KD, int R, int CINT, int SPLITK, int MODE>
__device__ __forceinline__ void conv_body(
    int bx, int by, int bz,
    const unsigned short* __restrict__ srcA, const unsigned short* __restrict__ srcB,
    const unsigned short* __restrict__ Apk, int COUT, float* __restrict__ po,
    const float* __restrict__ b0, const float* __restrict__ b1, const float* __restrict__ b2,
    unsigned short* __restrict__ t0, unsigned short* __restrict__ t1,
    unsigned short* __restrict__ t2)
{
    constexpr int PART   = CINT / SPLITK;
    constexpr int NCH    = PART / 32;
    constexpr int NSUB   = NCH * KD;
    constexpr int WR     = 8 + 2 * R;
    constexpr int WC     = 24 + 2 * R;
    constexpr int NPOS   = WR * WC;
    constexpr int NSLOTB = NPOS * 4;
    constexpr int RB     = (NSLOTB + 255) / 256;
    constexpr int AUNITS = KD * 4 * 64;
    constexpr int AR     = AUNITS / 256;
    __shared__ __align__(16) unsigned short Ab[2][AUNITS * 8];
    __shared__ __align__(16) unsigned short Bb[NPOS * 32];

    int f   = bx;
    int kk  = f % SPLITK;
    int cgb = f / SPLITK;
    int pxb = by;
    int img = bz;
    int t = threadIdx.x;
    int wave = t >> 6, lane = t & 63;
    int quad = lane >> 4, l15 = lane & 15;
    int r0 = pxb * 8;

    const int cibase = kk * PART;
    const unsigned short* src = (cibase >= 128) ? srcB : srcA;
    const int cioff0 = cibase & 127;
    const unsigned short* srcI = src + (size_t)img * 576 * 128;

    int posBase[3], pxs[3];
    #pragma unroll
    for (int s = 0; s < 3; ++s) {
        int px = pxb * 192 + wave * 48 + s * 16 + l15;
        pxs[s] = px;
        int pr = px / 24, pc = px % 24;
        posBase[s] = (pr - r0 + R) * WC + pc + R;
    }

    int goffB[RB]; bool gokB[RB];
    #pragma unroll
    for (int rr = 0; rr < RB; ++rr) {
        int idx = rr * 256 + wave * 64 + lane;
        int pos = idx >> 2, slotq = idx & 3;
        int gr = slotq ^ ((pos >> 1) & 3);
        int wr = pos / WC, wc = pos % WC;
        int grow = r0 - R + wr, gcol = wc - R;
        gokB[rr] = (idx < NSLOTB) && grow >= 0 && grow < 24 && gcol >= 0 && gcol < 24;
        goffB[rr] = (grow * 24 + gcol) * 128 + gr * 8;
    }

    auto stageB = [&](int ch) {
        const unsigned short* sp = srcI + cioff0 + ch * 32;
        #pragma unroll
        for (int rr = 0; rr < RB; ++rr) {
            if (gokB[rr]) {
                __builtin_amdgcn_global_load_lds(
                    (const GLOBAL_AS void*)(sp + goffB[rr]),
                    (LDS_AS void*)((char*)&Bb[0] + (size_t)(rr * 256 + wave * 64) * 16),
                    16, 0, 0);
            }
        }
    };
    auto stageA = [&](int sub, int buf) {
        const unsigned short* sp = Apk + ((size_t)((cgb * SPLITK + kk) * NSUB + sub)) * (AUNITS * 8);
        #pragma unroll
        for (int r = 0; r < AR; ++r) {
            int u0 = r * 256 + wave * 64;
            __builtin_amdgcn_global_load_lds(
                (const GLOBAL_AS void*)(sp + (size_t)(u0 + lane) * 8),
                (LDS_AS void*)((char*)&Ab[buf][0] + (size_t)u0 * 16),
                16, 0, 0);
        }
    };

    v4f acc[4][3];
    #pragma unroll
    for (int c = 0; c < 4; ++c)
        #pragma unroll
        for (int s = 0; s < 3; ++s)
            #pragma unroll
            for (int r = 0; r < 4; ++r) acc[c][s][r] = 0.f;

    {
        v8s zv;
        #pragma unroll
        for (int j = 0; j < 8; ++j) zv[j] = 0;
        for (int i = t; i < NPOS * 4; i += 256) ((v8s*)Bb)[i] = zv;
    }
    __syncthreads();
    stageB(0);
    stageA(0, 0);
    __syncthreads();

    int sub = 0;
    #pragma unroll 1
    for (int ch = 0; ch < NCH; ++ch) {
        #pragma unroll 1
        for (int g = 0; g < KD; ++g) {
            if (sub + 1 < NSUB) stageA(sub + 1, (sub + 1) & 1);
            const unsigned short* Ap = &Ab[sub & 1][0];
            #pragma unroll
            for (int tl = 0; tl < KD; ++tl) {
                int doff = (g - R) * WC + (tl - R);
                v8s a[4];
                #pragma unroll
                for (int c = 0; c < 4; ++c)
                    a[c] = *(const v8s*)&Ap[((tl * 4 + c) * 64 + l15 * 4 + quad) * 8];
                v8s b[3];
                #pragma unroll
                for (int s = 0; s < 3; ++s) {
                    int pos = posBase[s] + doff;
                    b[s] = *(const v8s*)&Bb[pos * 32 + ((quad ^ ((pos >> 1) & 3)) << 3)];
                }
                #pragma unroll
                for (int c = 0; c < 4; ++c)
                    #pragma unroll
                    for (int s = 0; s < 3; ++s)
                        acc[c][s] = __builtin_amdgcn_mfma_f32_16x16x32_bf16(a[c], b[s], acc[c][s], 0, 0, 0);
            }
            __syncthreads();
            ++sub;
        }
        if (ch + 1 < NCH) { stageB(ch + 1); __syncthreads(); }
    }

    if (MODE == 0) {
        float* out = po + (size_t)kk * ((size_t)SB * COUT * 576)
                   + ((size_t)img * COUT + cgb * 64) * 576;
        #pragma unroll
        for (int c = 0; c < 4; ++c)
            #pragma unroll
            for (int s = 0; s < 3; ++s)
                #pragma unroll
                for (int r = 0; r < 4; ++r) {
                    int col = c * 16 + quad * 4 + r;
                    out[(size_t)col * 576 + pxs[s]] = acc[c][s][r];
                }
    } else {
        #pragma unroll
        for (int c = 0; c < 4; ++c)
            #pragma unroll
            for (int s = 0; s < 3; ++s) {
                int px = pxs[s];
                #pragma unroll
                for (int r = 0; r < 4; ++r) {
                    int co = cgb * 64 + c * 16 + quad * 4 + r;
                    int which = co >> 7, cl = co & 127;
                    const float* bp = (which == 0) ? b0 : (which == 1) ? b1 : b2;
                    float v = acc[c][s][r] + bp[cl];
                    if (which == 0) {
                        t0[((size_t)img * 576 + px) * 128 + cl] = f2bf(v);
                    } else if (which == 1) {
                        int mt = px >> 4, l15m = px & 15;
                        int kb = cl >> 5, quadk = (cl >> 3) & 3, jj = cl & 7;
                        t1[(((size_t)img * 36 + mt) * 4 + kb) * 512 + (quadk * 16 + l15m) * 8 + jj] = f2bf(v);
                    } else {
                        int ctile = cl >> 4, l15v = cl & 15;
                        int sIdx = px >> 5, quadv = (px >> 3) & 3, jj = px & 7;
                        t2[(((size_t)img * 8 + ctile) * 18 + sIdx) * 512 + (quadv * 16 + l15v) * 8 + jj] = f2bf(v);
                    }
                }
            }
    }
}

template<int KD, int R, int CINT, int SPLITK, int MODE>
__global__ __launch_bounds__(256, 1) void conv_mfma(
    const unsigned short* __restrict__ srcA, const unsigned short* __restrict__ srcB,
    const unsigned short* __restrict__ Apk, int COUT, float* __restrict__ po,
    const float* __restrict__ b0, const float* __restrict__ b1, const float* __restrict__ b2,
    unsigned short* __restrict__ t0, unsigned short* __restrict__ t1,
    unsigned short* __restrict__ t2)
{
    conv_body<KD, R, CINT, SPLITK, MODE>(blockIdx.x, blockIdx.y, blockIdx.z,
        srcA, srcB, Apk, COUT, po, b0, b1, b2, t0, t1, t2);
}

// ---------------------------------------------------------------- yt (MFMA) -> K-packed
__device__ __forceinline__ void yt_body(
    int mt, int img,
    const unsigned short* __restrict__ hT, const unsigned short* __restrict__ Wcb,
    unsigned short* __restrict__ KFi)
{
    int t = threadIdx.x, wave = t >> 6, lane = t & 63;
    int q = lane >> 4, l15 = lane & 15;
    int n0 = mt * 16;
    v4f acc[2];
    #pragma unroll
    for (int ct = 0; ct < 2; ++ct)
        #pragma unroll
        for (int r = 0; r < 4; ++r) acc[ct][r] = 0.f;
    #pragma unroll
    for (int kk = 0; kk < 4; ++kk) {
        v8s b = *(const v8s*)(hT + ((size_t)img * 576 + n0 + l15) * 128 + kk * 32 + q * 8);
        #pragma unroll
        for (int ct = 0; ct < 2; ++ct) {
            v8s a = *(const v8s*)(Wcb + (size_t)((wave * 2 + ct) * 16 + l15) * 128 + kk * 32 + q * 8);
            acc[ct] = __builtin_amdgcn_mfma_f32_16x16x32_bf16(a, b, acc[ct], 0, 0, 0);
        }
    }
    #pragma unroll
    for (int ct = 0; ct < 2; ++ct) {
        #pragma unroll
        for (int r = 0; r < 4; ++r) {
            int co = (wave * 2 + ct) * 16 + q * 4 + r;
            int kk = co >> 5, quadk = (co >> 3) & 3, j = co & 7;
            KFi[(((size_t)img * 36 + mt) * 4 + kk) * 512 + (quadk * 16 + l15) * 8 + j]
                = f2bf(acc[ct][r]);
        }
    }
}

// ---------------------- merged conv3 (180 blocks) + yt (360 blocks) — both need only hT16
__global__ __launch_bounds__(256, 1) void conv3_yt_kernel(
    const unsigned short* __restrict__ hT, const unsigned short* __restrict__ Wp3,
    const float* __restrict__ Wf_b, const float* __restrict__ Wh_b,
    const float* __restrict__ Wl_b,
    unsigned short* __restrict__ ftT, unsigned short* __restrict__ KFa,
    unsigned short* __restrict__ VFa,
    const unsigned short* __restrict__ Wcb, unsigned short* __restrict__ KFi)
{
    int bid = blockIdx.x;
    if (bid < 180) {
        conv_body<3, 1, 128, 1, 1>(bid % 6, (bid / 6) % 3, bid / 18,
            hT, hT, Wp3, 384, nullptr, Wf_b, Wh_b, Wl_b, ftT, KFa, VFa);
    } else {
        int b2 = bid - 180;
        yt_body(b2 % 36, b2 / 36, hT, Wcb, KFi);
    }
}

// ---------------------------------------------------- MFMA flash attention (merged)
// 32-row Q tiles; 1D grid with bijective XCD chunk swizzle + kimg-major pair order
// (R5: keeps each kimg's K/V on 1-2 XCD L2s). Output at original pp index.
__global__ __launch_bounds__(256) void attn_merged(
    const unsigned short* __restrict__ QTi, const unsigned short* __restrict__ KFa,
    const unsigned short* __restrict__ VFa, float* __restrict__ Of,
    const float* __restrict__ addsrc, const float* __restrict__ alpha,
    const unsigned short* __restrict__ QTe, const unsigned short* __restrict__ KFe,
    const unsigned short* __restrict__ VFe, unsigned short* __restrict__ Oh,
    float* __restrict__ wpart)
{
    __shared__ __align__(16) unsigned short P[32 * 576];
    __shared__ float redmx[4][32];
    __shared__ float redsm[4][32];
    int t = threadIdx.x;
    int wave = t >> 6, lane = t & 63;
    int q = lane >> 4, l15 = lane & 15;

    // bijective swizzle over 900 = 8*112 + 4 blocks (m204 variant)
    int bid = blockIdx.x;
    int xcd = bid & 7, slot = bid >> 3;
    int gs = (xcd < 4) ? xcd * 113 + slot : 452 + (xcd - 4) * 112 + slot;
    int p = gs / 18;
    int mt2 = gs - p * 18;
    int n0 = mt2 * 32;

    bool intra = (p < SB);
    int pp = 0;
    const unsigned short *Qp, *Kp, *Vp;
    if (intra) {
        Qp = QTi + ((size_t)p * 576 + n0) * 128;
        Kp = KFa + (size_t)p * 36 * 4 * 512;
        Vp = VFa + (size_t)p * 8 * 18 * 512;
    } else {
        int pe = p - SB;                       // j-major enumeration
        int j = pe >> 3; int t2 = pe & 7;
        int b = t2 & 1;  int ii = t2 >> 1;
        int i = ii + (ii >= j ? 1 : 0);
        int qimg = i * 2 + b, kimg = j * 2 + b;
        pp = (i * 4 + (j - (j > i ? 1 : 0))) * 2 + b;  // original output index
        Qp = QTe + ((size_t)qimg * 576 + n0) * 128;
        Kp = KFe + (size_t)kimg * 36 * 4 * 512;
        Vp = VFe + (size_t)kimg * 8 * 18 * 512;
    }

    v8s aq[2][4];
    #pragma unroll
    for (int qt = 0; qt < 2; ++qt)
        #pragma unroll
        for (int kk = 0; kk < 4; ++kk)
            aq[qt][kk] = *(const v8s*)(Qp + (size_t)(qt * 16 + l15) * 128 + kk * 32 + q * 8);

    v4f S[2][9];
    #pragma unroll
    for (int qt = 0; qt < 2; ++qt)
        #pragma unroll
        for (int i = 0; i < 9; ++i)
            #pragma unroll
            for (int r = 0; r < 4; ++r) S[qt][i][r] = 0.f;

    #pragma unroll
    for (int i = 0; i < 9; ++i) {
        int mtk = wave * 9 + i;
        #pragma unroll
        for (int kk = 0; kk < 4; ++kk) {
            v8s b = *(const v8s*)(Kp + ((size_t)(mtk * 4 + kk)) * 512 + lane * 8);
            S[0][i] = __builtin_amdgcn_mfma_f32_16x16x32_bf16(aq[0][kk], b, S[0][i], 0, 0, 0);
            S[1][i] = __builtin_amdgcn_mfma_f32_16x16x32_bf16(aq[1][kk], b, S[1][i], 0, 0, 0);
        }
    }

    #pragma unroll
    for (int qt = 0; qt < 2; ++qt) {
        #pragma unroll
        for (int r = 0; r < 4; ++r) {
            float m = S[qt][0][r];
            #pragma unroll
            for (int i = 1; i < 9; ++i) m = fmaxf(m, S[qt][i][r]);
            #pragma unroll
            for (int off = 1; off < 16; off <<= 1) m = fmaxf(m, __shfl_xor(m, off));
            if (l15 == 0) redmx[wave][qt * 16 + q * 4 + r] = m;
        }
    }
    __syncthreads();
    float sum[2][4];
    #pragma unroll
    for (int qt = 0; qt < 2; ++qt) {
        #pragma unroll
        for (int r = 0; r < 4; ++r) {
            int rr = qt * 16 + q * 4 + r;
            float g = fmaxf(fmaxf(redmx[0][rr], redmx[1][rr]),
                            fmaxf(redmx[2][rr], redmx[3][rr]));
            float s = 0.f;
            #pragma unroll
            for (int i = 0; i < 9; ++i) { float e = __expf(S[qt][i][r] - g); S[qt][i][r] = e; s += e; }
            #pragma unroll
            for (int off = 1; off < 16; off <<= 1) s += __shfl_xor(s, off);
            sum[qt][r] = s;
        }
    }
    if (l15 == 0) {
        #pragma unroll
        for (int qt = 0; qt < 2; ++qt)
            #pragma unroll
            for (int r = 0; r < 4; ++r) redsm[wave][qt * 16 + q * 4 + r] = sum[qt][r];
    }
    #pragma unroll
    for (int qt = 0; qt < 2; ++qt) {
        #pragma unroll
        for (int i = 0; i < 9; ++i) {
            int m = (wave * 9 + i) * 16 + l15;
            int cm = m >> 3, mo = m & 7;
            #pragma unroll
            for (int r = 0; r < 4; ++r) {
                int n = qt * 16 + q * 4 + r;
                P[n * 576 + ((cm ^ (n & 7)) << 3) + mo] = f2bf(S[qt][i][r]);
            }
        }
    }
    __syncthreads();
    float inv[2][4];
    #pragma unroll
    for (int qt = 0; qt < 2; ++qt)
        #pragma unroll
        for (int r = 0; r < 4; ++r) {
            int rr = qt * 16 + q * 4 + r;
            inv[qt][r] = 1.f / (redsm[0][rr] + redsm[1][rr] + redsm[2][rr] + redsm[3][rr]);
        }

    v4f o[2][2];
    #pragma unroll
    for (int qt = 0; qt < 2; ++qt)
        #pragma unroll
        for (int ct = 0; ct < 2; ++ct)
            #pragma unroll
            for (int r = 0; r < 4; ++r) o[qt][ct][r] = 0.f;

    for (int s = 0; s < 18; ++s) {
        int cm = s * 4 + q;
        v8s a0 = *(const v8s*)&P[l15 * 576 + ((cm ^ (l15 & 7)) << 3)];
        v8s a1 = *(const v8s*)&P[(16 + l15) * 576 + ((cm ^ (l15 & 7)) << 3)];
        #pragma unroll
        for (int ct = 0; ct < 2; ++ct) {
            int ctile = wave * 2 + ct;
            v8s b = *(const v8s*)(Vp + ((size_t)(ctile * 18 + s)) * 512 + lane * 8);
            o[0][ct] = __builtin_amdgcn_mfma_f32_16x16x32_bf16(a0, b, o[0][ct], 0, 0, 0);
            o[1][ct] = __builtin_amdgcn_mfma_f32_16x16x32_bf16(a1, b, o[1][ct], 0, 0, 0);
        }
    }

    if (intra) {
        float al = alpha[0];
        #pragma unroll
        for (int qt = 0; qt < 2; ++qt)
            #pragma unroll
            for (int ct = 0; ct < 2; ++ct) {
                int c = (wave * 2 + ct) * 16 + l15;
                size_t base = ((size_t)p * 128 + c) * 576 + n0 + qt * 16 + q * 4;
                #pragma unroll
                for (int r = 0; r < 4; ++r)
                    Of[base + r] = al * o[qt][ct][r] * inv[qt][r] + addsrc[base + r];
            }
    } else {
        #pragma unroll
        for (int ct = 0; ct < 2; ++ct) {
            int c = (wave * 2 + ct) * 16 + l15;
            float sums[9];
            #pragma unroll
            for (int k = 0; k < 9; ++k) sums[k] = 0.f;
            #pragma unroll
            for (int qt = 0; qt < 2; ++qt) {
                size_t base = ((size_t)pp * 128 + c) * 576 + n0 + qt * 16 + q * 4;
                #pragma unroll
                for (int r = 0; r < 4; ++r) {
                    unsigned short hb = f2bf(o[qt][ct][r] * inv[qt][r]);
                    Oh[base + r] = hb;
                    float v = bf2f(hb);
                    int px = n0 + qt * 16 + q * 4 + r;
                    int row = px / 24, col = px % 24;
                    sums[0] += v;
                    if (row == 0)  sums[1] += v;
                    if (row == 23) sums[2] += v;
                    if (col == 0)  sums[3] += v;
                    if (col == 23) sums[4] += v;
                    if (px == 0)   sums[5] += v;
                    if (px == 23)  sums[6] += v;
                    if (px == 552) sums[7] += v;
                    if (px == 575) sums[8] += v;
                }
            }
            #pragma unroll
            for (int k = 0; k < 9; ++k) {
                sums[k] += __shfl_xor(sums[k], 16);
                sums[k] += __shfl_xor(sums[k], 32);
            }
            if (q == 0) {
                float* wp = wpart + (((size_t)pp * 18 + mt2) * 9) * 128 + c;
                #pragma unroll
                for (int k = 0; k < 9; ++k) wp[k * 128] = sums[k];
            }
        }
    }
}

// gate: reduce per-mt2 partials (L2-resident), 2-way split dot via WgT
__global__ __launch_bounds__(256) void g_kernel(
    const float* __restrict__ wpart, const float* __restrict__ WgT,
    const float* __restrict__ Wgb, float* __restrict__ g)
{
    __shared__ float sw[C_ * 9];
    __shared__ float acc2[256];
    int pair = blockIdx.x; int t = threadIdx.x;
    int co = t & 127, half = t >> 7;
    const float* base = wpart + (size_t)pair * 18 * 9 * 128 + co;
    float raw[9];
    #pragma unroll
    for (int k = 0; k < 9; ++k) raw[k] = 0.f;
    for (int mt = half; mt < 18; mt += 2) {
        #pragma unroll
        for (int k = 0; k < 9; ++k) raw[k] += base[(mt * 9 + k) * 128];
    }
    if (half == 1) {
        #pragma unroll
        for (int k = 0; k < 9; ++k) sw[co * 9 + k] = raw[k];
    }
    __syncthreads();
    if (half == 0) {
        #pragma unroll
        for (int k = 0; k < 9; ++k) raw[k] += sw[co * 9 + k];
        float rowsub[3] = {raw[2], 0.f, raw[1]};
        float colsub[3] = {raw[4], 0.f, raw[3]};
        float corner[9] = {raw[8], 0.f, raw[7], 0.f, 0.f, 0.f, raw[6], 0.f, raw[5]};
        #pragma unroll
        for (int ky = 0; ky < 3; ++ky)
            #pragma unroll
            for (int kx = 0; kx < 3; ++kx)
                sw[co * 9 + ky * 3 + kx] = raw[0] - rowsub[ky] - colsub[kx] + corner[ky * 3 + kx];
    }
    __syncthreads();
    float acc = 0.f;
    const float* wg = WgT + (size_t)half * 576 * 128 + co;
    const float* swh = sw + half * 576;
    for (int i = 0; i < 576; ++i) acc += wg[(size_t)i * 128] * swh[i];
    acc2[t] = acc;
    __syncthreads();
    if (half == 0) {
        float m = (acc + acc2[t + 128]) * (1.f / 576.f) + Wgb[co];
        g[pair * C_ + co] = 1.f / (1.f + __expf(-m));
    }
}

// ----------------------- fused msg compute + transpose-cast -> msgT16 [px][c]
__global__ __launch_bounds__(256) void msg_tc_kernel(
    const float* __restrict__ eii, const unsigned short* __restrict__ mji,
    const float* __restrict__ g, const float* __restrict__ bn_gamma,
    const float* __restrict__ bn_beta, const float* __restrict__ intra_w,
    const float* __restrict__ inter_w, unsigned short* __restrict__ msgT)
{
    __shared__ float tile[128][9];
    int img = blockIdx.y, px0 = blockIdx.x * 8, t = threadIdx.x;
    int s = img >> 1, b = img & 1;
    float iw = intra_w[0], ew = inter_w[0];
    #pragma unroll
    for (int i = 0; i < 4; ++i) {
        int e = i * 256 + t; int ci = e >> 3; int pxl = e & 7;
        int px = px0 + pxl;
        float scale = bn_gamma[ci] * rsqrtf(1.f + 1e-5f);
        float acc = 0.f;
        #pragma unroll
        for (int jj = 0; jj < 4; ++jj) {
            int pidx = (s * 4 + jj) * 2 + b;
            acc += g[pidx * C_ + ci] * bf2f(mji[((size_t)pidx * C_ + ci) * N_ + px]);
        }
        float inter = scale * acc + 4.f * bn_beta[ci];
        tile[ci][pxl] = iw * eii[((size_t)img * C_ + ci) * N_ + px] + ew * inter;
    }
    __syncthreads();
    #pragma unroll
    for (int i = 0; i < 4; ++i) {
        int e = i * 256 + t; int pxl = e >> 7; int ci = e & 127;
        msgT[((size_t)img * 576 + px0 + pxl) * 128 + ci] = f2bf(tile[ci][pxl]);
    }
}

// -------- fused GRU update + next-iter transpose/packs (hT [px][c], VF pack)
__global__ __launch_bounds__(256) void update_tc_kernel(
    const float* __restrict__ zrp, const float* __restrict__ zrb,
    const float* __restrict__ hhp, const float* __restrict__ ghb,
    const float* __restrict__ h, float* __restrict__ out,
    unsigned short* __restrict__ hTn, unsigned short* __restrict__ VFn, int last)
{
    const size_t ZP = (size_t)SB * C2 * N_;
    const size_t HP = (size_t)SB * C_ * N_;
    __shared__ float tile[128][9];
    int img = blockIdx.y, px0 = blockIdx.x * 8, t = threadIdx.x;
    #pragma unroll
    for (int i = 0; i < 4; ++i) {
        int e = i * 256 + t; int ci = e >> 3; int pxl = e & 7;
        int px = px0 + pxl;
        size_t zi = ((size_t)img * C2 + ci) * N_ + px;
        float za = zrb[ci];
        #pragma unroll
        for (int k = 0; k < ZRSPLIT; ++k) za += zrp[k * ZP + zi];
        float z = 1.f / (1.f + __expf(-za));
        size_t hi = ((size_t)img * C_ + ci) * N_ + px;
        float ha = ghb[ci];
        #pragma unroll
        for (int k = 0; k < 4; ++k) ha += hhp[k * HP + hi];
        float hh = tanhf(ha);
        float o = (2.f - z) * h[hi] + z * hh;
        out[hi] = o;
        tile[ci][pxl] = o;
        if (!last) {
            int ctile = ci >> 4, l15v = ci & 15;
            int sIdx = px >> 5, quadv = (px >> 3) & 3, j = px & 7;
            VFn[(((size_t)img * 8 + ctile) * 18 + sIdx) * 512 + (quadv * 16 + l15v) * 8 + j] = f2bf(o);
        }
    }
    if (!last) {
        __syncthreads();
        #pragma unroll
        for (int i = 0; i < 4; ++i) {
            int e = i * 256 + t; int pxl = e >> 7; int ci = e & 127;
            hTn[((size_t)img * 576 + px0 + pxl) * 128 + ci] = f2bf(tile[ci][pxl]);
        }
    }
}

// ------------------------------------------------------------------- launcher
extern "C" void kernel_launch(void* const* d_in, const int* in_sizes, int n_in,
                              void* d_out, int out_size, void* d_ws, size_t ws_size,
                              hipStream_t stream)
{
    const float* x      = (const float*)d_in[0];
    const float* Wf_w   = (const float*)d_in[1];
    const float* Wf_b   = (const float*)d_in[2];
    const float* Wh_w   = (const float*)d_in[3];
    const float* Wh_b   = (const float*)d_in[4];
    const float* Wl_w   = (const float*)d_in[5];
    const float* Wl_b   = (const float*)d_in[6];
    const float* alpha  = (const float*)d_in[7];
    const float* Wc     = (const float*)d_in[8];
    const float* Wg_w   = (const float*)d_in[9];
    const float* Wg_b   = (const float*)d_in[10];
    const float* bng    = (const float*)d_in[11];
    const float* bnb    = (const float*)d_in[12];
    const float* zr_w   = (const float*)d_in[13];
    const float* zr_b   = (const float*)d_in[14];
    const float* gh_w   = (const float*)d_in[15];
    const float* gh_b   = (const float*)d_in[16];
    const float* intraw = (const float*)d_in[17];
    const float* interw = (const float*)d_in[18];
    float* outp = (float*)d_out;

    float* f = (float*)d_ws;
    const size_t SZ = (size_t)SB * C_ * N_;
    float* hbuf  = f; f += SZ;
    float* eii   = f; f += SZ;
    float* zrp   = f; f += (size_t)ZRSPLIT * SB * C2 * N_;
    float* hhp   = f; f += 4 * SZ;
    float* wpart = f; f += (size_t)NPAIR * 18 * 9 * 128;
    float* gbuf  = f; f += (size_t)NPAIR * C_;
    float* WgT   = f; f += (size_t)128 * 1152;
    unsigned short* us = (unsigned short*)f;
    unsigned short* mji16  = us; us += (size_t)NPAIR * C_ * N_;
    unsigned short* hT16   = us; us += SZ;
    unsigned short* hc16   = us; us += SZ;           // VFi inter / rhbT16
    unsigned short* msgT16 = us; us += SZ;
    unsigned short* ftT    = us; us += SZ;           // Q intra
    unsigned short* KFa    = us; us += SZ;
    unsigned short* VFa    = us; us += SZ;
    unsigned short* Wp3    = us; us += (size_t)384 * 1152;
    unsigned short* Wpzr   = us; us += (size_t)256 * 6400;
    unsigned short* Wph    = us; us += (size_t)128 * 6400;
    unsigned short* Wcb    = us; us += (size_t)128 * 128;
    unsigned short* KFi    = us; us += SZ;

    unsigned short* VFi    = hc16;
    unsigned short* rhbT16 = hc16;

    // all weight packs + initial transpose/pack of x in ONE launch
    pack_all_kernel<<<NB_A3 + NB_A5ZR + NB_A5H + NB_WC + NB_WGT + NB_TC, 256, 0, stream>>>(
        Wf_w, Wh_w, Wl_w, Wp3, zr_w, Wpzr, gh_w, Wph, Wc, Wcb, Wg_w, WgT,
        x, hT16, VFi);

    const float* hcur = x;
    for (int it = 0; it < 3; ++it) {
        float* hout = (it == 2) ? outp : hbuf;

        conv3_yt_kernel<<<540, 256, 0, stream>>>(
            hT16, Wp3, Wf_b, Wh_b, Wl_b, ftT, KFa, VFa, Wcb, KFi);
        attn_merged<<<900, 256, 0, stream>>>(
            ftT, KFa, VFa, eii, hcur, alpha, hT16, KFi, VFi, mji16, wpart);
        g_kernel<<<NPAIR, 256, 0, stream>>>(wpart, WgT, Wg_b, gbuf);
        msg_tc_kernel<<<dim3(72, SB), 256, 0, stream>>>(
            eii, mji16, gbuf, bng, bnb, intraw, interw, msgT16);
        // conv_zr at SPLITK=2: 240 blocks (1/CU, 20 subs) — same LDS-bound wall time
        // as 480@2/CU, half the f32 partial traffic (pack layout unchanged, see packA5)
        conv_mfma<5, 2, 256, ZRSPLIT, 0><<<dim3(4 * ZRSPLIT, 3, SB), 256, 0, stream>>>(
            msgT16, hT16, Wpzr, 256, zrp, nullptr, nullptr, nullptr, nullptr, nullptr, nullptr);
        tc_kernel<<<dim3(72, SB), 256, 0, stream>>>(hcur, zrp, zr_b, rhbT16, nullptr);
        conv_mfma<5, 2, 256, 4, 0><<<dim3(8, 3, SB), 256, 0, stream>>>(
            msgT16, rhbT16, Wph, 128, hhp, nullptr, nullptr, nullptr, nullptr, nullptr, nullptr);
        update_tc_kernel<<<dim3(72, SB), 256, 0, stream>>>(
            zrp, zr_b, hhp, gh_b, hcur, hout, hT16, VFi, (it == 2) ? 1 : 0);
        hcur = hout;
    }
}

// Round 9
// 502.273 us; speedup vs baseline: 1.0728x; 1.0728x over previous
//
#include <hip/hip_runtime.h>
#include <math.h>

#define S_  5
#define B_  2
#define C_  128
#define N_  576
#define SB  10
#define NPAIR 40
#define C2  256
#define ZRSPLIT 4   // R8 lesson: conv5 needs 480 blocks (2/CU) to hide barrier drains

typedef short v8s __attribute__((ext_vector_type(8)));
typedef float v4f __attribute__((ext_vector_type(4)));

#define GLOBAL_AS __attribute__((address_space(1)))
#define LDS_AS    __attribute__((address_space(3)))

__device__ __forceinline__ unsigned short f2bf(float f) {
    union { float f; unsigned u; } v; v.f = f;
    unsigned r = (v.u + 0x7FFF + ((v.u >> 16) & 1)) >> 16;
    return (unsigned short)r;
}
__device__ __forceinline__ float bf2f(unsigned short h) {
    union { unsigned u; float f; } v; v.u = ((unsigned)h) << 16;
    return v.f;
}

// ------------------------------------------------------------------ weight pack bodies
// Fragment-major A: [cgb][kk][ch][g][tap_l][c(4)][l15(16)][quad(4)][j(8)]
__device__ __forceinline__ void packA5_body(int idx, const float* __restrict__ w,
                                            unsigned short* __restrict__ Apk, int M)
{
    if (idx >= M * 6400) return;
    int r = idx;
    int j = r & 7;      r >>= 3;
    int quad = r & 3;   r >>= 2;
    int l15 = r & 15;   r >>= 4;
    int c = r & 3;      r >>= 2;
    int tap_l = r % 5;  r /= 5;
    int g = r % 5;      r /= 5;
    int ch = r & 1;     r >>= 1;
    int kk = r & 3;     r >>= 2;
    int cgb = r;
    int co = cgb * 64 + c * 16 + l15;
    int ci = kk * 64 + ch * 32 + quad * 8 + j;
    int tap = g * 5 + tap_l;
    Apk[idx] = f2bf(w[((size_t)co * 256 + ci) * 25 + tap]);
}
__device__ __forceinline__ void packA3_body(int idx, const float* __restrict__ wf,
                                            const float* __restrict__ wh,
                                            const float* __restrict__ wl,
                                            unsigned short* __restrict__ Apk)
{
    if (idx >= 384 * 1152) return;
    int r = idx;
    int j = r & 7;      r >>= 3;
    int quad = r & 3;   r >>= 2;
    int l15 = r & 15;   r >>= 4;
    int c = r & 3;      r >>= 2;
    int tap_l = r % 3;  r /= 3;
    int g = r % 3;      r /= 3;
    int ch = r & 1;     r >>= 1;
    int kk = r & 1;     r >>= 1;
    int cgb = r;
    int co = cgb * 64 + c * 16 + l15;
    const float* w = (co < 128) ? wf : (co < 256) ? wh : wl;
    int cl = co & 127;
    int ci = kk * 64 + ch * 32 + quad * 8 + j;
    int tap = g * 3 + tap_l;
    Apk[idx] = f2bf(w[((size_t)cl * 128 + ci) * 9 + tap]);
}
__device__ __forceinline__ void packWc_body(int idx, const float* __restrict__ w,
                                            unsigned short* __restrict__ o)
{
    if (idx < 128 * 128) o[idx] = f2bf(w[idx]);
}
// Wg[co][i] -> WgT[i][co]  (coalesced g_kernel reads)
__device__ __forceinline__ void packWgT_body(int idx, const float* __restrict__ w,
                                             float* __restrict__ o)
{
    if (idx >= 128 * 1152) return;
    int co = idx & 127, i = idx >> 7;
    o[(size_t)i * 128 + co] = w[(size_t)co * 1152 + i];
}

// ---------------------------------------------- transpose-cast body (x at it=0, rhb)
__device__ __forceinline__ void tc_body(
    int px0, int img,
    const float* __restrict__ src, const float* __restrict__ zrp,
    const float* __restrict__ zrb,
    unsigned short* __restrict__ dst, unsigned short* __restrict__ vfd)
{
    const size_t PLANE = (size_t)SB * C2 * N_;
    __shared__ float tile[128][9];
    int t = threadIdx.x;
    #pragma unroll
    for (int i = 0; i < 4; ++i) {
        int e = i * 256 + t; int ci = e >> 3; int px = e & 7;
        float v = src[((size_t)img * 128 + ci) * 576 + px0 + px];
        if (zrp) {
            size_t zi = ((size_t)img * C2 + 128 + ci) * 576 + px0 + px;
            float a = zrb[128 + ci];
            #pragma unroll
            for (int k = 0; k < ZRSPLIT; ++k) a += zrp[k * PLANE + zi];
            v *= 1.f / (1.f + __expf(-a));
        }
        tile[ci][px] = v;
        if (vfd) {
            int m = px0 + px;
            int ctile = ci >> 4, l15v = ci & 15;
            int sIdx = m >> 5, quadv = (m >> 3) & 3, j = m & 7;
            vfd[(((size_t)img * 8 + ctile) * 18 + sIdx) * 512 + (quadv * 16 + l15v) * 8 + j] = f2bf(v);
        }
    }
    __syncthreads();
    #pragma unroll
    for (int i = 0; i < 4; ++i) {
        int e = i * 256 + t; int pxl = e >> 7; int ci = e & 127;
        dst[((size_t)img * 576 + px0 + pxl) * 128 + ci] = f2bf(tile[ci][pxl]);
    }
}

// loop-phase tc (rhb path) stays a standalone kernel
__global__ __launch_bounds__(256) void tc_kernel(
    const float* __restrict__ src, const float* __restrict__ zrp,
    const float* __restrict__ zrb,
    unsigned short* __restrict__ dst, unsigned short* __restrict__ vfd)
{
    tc_body(blockIdx.x * 8, blockIdx.y, src, zrp, zrb, dst, vfd);
}

// ----------------------------------------- merged setup: all packs + initial tc
// pack bodies: 4 elements/thread (1024/block) — 4x MLP per thread, 1/4 the blocks
#define NB_A3   432
#define NB_A5ZR 1600
#define NB_A5H  800
#define NB_WC   16
#define NB_WGT  144
#define NB_TC   720
__global__ __launch_bounds__(256) void pack_all_kernel(
    const float* __restrict__ Wf_w, const float* __restrict__ Wh_w,
    const float* __restrict__ Wl_w, unsigned short* __restrict__ Wp3,
    const float* __restrict__ zr_w, unsigned short* __restrict__ Wpzr,
    const float* __restrict__ gh_w, unsigned short* __restrict__ Wph,
    const float* __restrict__ Wc,  unsigned short* __restrict__ Wcb,
    const float* __restrict__ Wg_w, float* __restrict__ WgT,
    const float* __restrict__ x, unsigned short* __restrict__ hT16,
    unsigned short* __restrict__ VFi)
{
    int bid = blockIdx.x, t = threadIdx.x;
    if (bid < NB_A3) {
        int base = bid * 1024 + t;
        #pragma unroll
        for (int k = 0; k < 4; ++k) packA3_body(base + k * 256, Wf_w, Wh_w, Wl_w, Wp3);
    } else if (bid < NB_A3 + NB_A5ZR) {
        int base = (bid - NB_A3) * 1024 + t;
        #pragma unroll
        for (int k = 0; k < 4; ++k) packA5_body(base + k * 256, zr_w, Wpzr, 256);
    } else if (bid < NB_A3 + NB_A5ZR + NB_A5H) {
        int base = (bid - NB_A3 - NB_A5ZR) * 1024 + t;
        #pragma unroll
        for (int k = 0; k < 4; ++k) packA5_body(base + k * 256, gh_w, Wph, 128);
    } else if (bid < NB_A3 + NB_A5ZR + NB_A5H + NB_WC) {
        int base = (bid - NB_A3 - NB_A5ZR - NB_A5H) * 1024 + t;
        #pragma unroll
        for (int k = 0; k < 4; ++k) packWc_body(base + k * 256, Wc, Wcb);
    } else if (bid < NB_A3 + NB_A5ZR + NB_A5H + NB_WC + NB_WGT) {
        int base = (bid - NB_A3 - NB_A5ZR - NB_A5H - NB_WC) * 1024 + t;
        #pragma unroll
        for (int k = 0; k < 4; ++k) packWgT_body(base + k * 256, Wg_w, WgT);
    } else {
        int b2 = bid - (NB_A3 + NB_A5ZR + NB_A5H + NB_WC + NB_WGT);
        tc_body((b2 % 72) * 8, b2 / 72, x, nullptr, nullptr, hT16, VFi);
    }
}

// ------------------------------------------------------ MFMA implicit-GEMM conv v7 (R3)
// MODE 0: f32 partial planes per kk (5x5 convs, SPLITK=4)
// MODE 1: conv3 full-K fused epilogue: +bias, write ftT(Q) / KFa(K-pack) / VFa(V-pack)
// Capacity law (R6+R8): conv5 needs BOTH 2 blocks/CU (hide per-sub barrier drains)
// AND grid <= 512 (one resident round). SPLITK=4 @ 480 blocks is the unique fit.
template<int KD, int R, int CINT, int SPLITK, int MODE>
__device__ __forceinline__ void conv_body(
    int bx, int by, int bz,
    const unsigned short* __restrict__ srcA, const unsigned short* __restrict__ srcB,
    const unsigned short* __restrict__ Apk, int COUT, float* __restrict__ po,
    const float* __restrict__ b0, const float* __restrict__ b1, const float* __restrict__ b2,
    unsigned short* __restrict__ t0, unsigned short* __restrict__ t1,
    unsigned short* __restrict__ t2)
{
    constexpr int PART   = CINT / SPLITK;
    constexpr int NCH    = PART / 32;
    constexpr int NSUB   = NCH * KD;
    constexpr int WR     = 8 + 2 * R;
    constexpr int WC     = 24 + 2 * R;
    constexpr int NPOS   = WR * WC;
    constexpr int NSLOTB = NPOS * 4;
    constexpr int RB     = (NSLOTB + 255) / 256;
    constexpr int AUNITS = KD * 4 * 64;
    constexpr int AR     = AUNITS / 256;
    __shared__ __align__(16) unsigned short Ab[2][AUNITS * 8];
    __shared__ __align__(16) unsigned short Bb[NPOS * 32];

    int f   = bx;
    int kk  = f % SPLITK;
    int cgb = f / SPLITK;
    int pxb = by;
    int img = bz;
    int t = threadIdx.x;
    int wave = t >> 6, lane = t & 63;
    int quad = lane >> 4, l15 = lane & 15;
    int r0 = pxb * 8;

    const int cibase = kk * PART;
    const unsigned short* src = (cibase >= 128) ? srcB : srcA;
    const int cioff0 = cibase & 127;
    const unsigned short* srcI = src + (size_t)img * 576 * 128;

    int posBase[3], pxs[3];
    #pragma unroll
    for (int s = 0; s < 3; ++s) {
        int px = pxb * 192 + wave * 48 + s * 16 + l15;
        pxs[s] = px;
        int pr = px / 24, pc = px % 24;
        posBase[s] = (pr - r0 + R) * WC + pc + R;
    }

    int goffB[RB]; bool gokB[RB];
    #pragma unroll
    for (int rr = 0; rr < RB; ++rr) {
        int idx = rr * 256 + wave * 64 + lane;
        int pos = idx >> 2, slotq = idx & 3;
        int gr = slotq ^ ((pos >> 1) & 3);
        int wr = pos / WC, wc = pos % WC;
        int grow = r0 - R + wr, gcol = wc - R;
        gokB[rr] = (idx < NSLOTB) && grow >= 0 && grow < 24 && gcol >= 0 && gcol < 24;
        goffB[rr] = (grow * 24 + gcol) * 128 + gr * 8;
    }

    auto stageB = [&](int ch) {
        const unsigned short* sp = srcI + cioff0 + ch * 32;
        #pragma unroll
        for (int rr = 0; rr < RB; ++rr) {
            if (gokB[rr]) {
                __builtin_amdgcn_global_load_lds(
                    (const GLOBAL_AS void*)(sp + goffB[rr]),
                    (LDS_AS void*)((char*)&Bb[0] + (size_t)(rr * 256 + wave * 64) * 16),
                    16, 0, 0);
            }
        }
    };
    auto stageA = [&](int sub, int buf) {
        const unsigned short* sp = Apk + ((size_t)((cgb * SPLITK + kk) * NSUB + sub)) * (AUNITS * 8);
        #pragma unroll
        for (int r = 0; r < AR; ++r) {
            int u0 = r * 256 + wave * 64;
            __builtin_amdgcn_global_load_lds(
                (const GLOBAL_AS void*)(sp + (size_t)(u0 + lane) * 8),
                (LDS_AS void*)((char*)&Ab[buf][0] + (size_t)u0 * 16),
                16, 0, 0);
        }
    };

    v4f acc[4][3];
    #pragma unroll
    for (int c = 0; c < 4; ++c)
        #pragma unroll
        for (int s = 0; s < 3; ++s)
            #pragma unroll
            for (int r = 0; r < 4; ++r) acc[c][s][r] = 0.f;

    {
        v8s zv;
        #pragma unroll
        for (int j = 0; j < 8; ++j) zv[j] = 0;
        for (int i = t; i < NPOS * 4; i += 256) ((v8s*)Bb)[i] = zv;
    }
    __syncthreads();
    stageB(0);
    stageA(0, 0);
    __syncthreads();

    int sub = 0;
    #pragma unroll 1
    for (int ch = 0; ch < NCH; ++ch) {
        #pragma unroll 1
        for (int g = 0; g < KD; ++g) {
            if (sub + 1 < NSUB) stageA(sub + 1, (sub + 1) & 1);
            const unsigned short* Ap = &Ab[sub & 1][0];
            #pragma unroll
            for (int tl = 0; tl < KD; ++tl) {
                int doff = (g - R) * WC + (tl - R);
                v8s a[4];
                #pragma unroll
                for (int c = 0; c < 4; ++c)
                    a[c] = *(const v8s*)&Ap[((tl * 4 + c) * 64 + l15 * 4 + quad) * 8];
                v8s b[3];
                #pragma unroll
                for (int s = 0; s < 3; ++s) {
                    int pos = posBase[s] + doff;
                    b[s] = *(const v8s*)&Bb[pos * 32 + ((quad ^ ((pos >> 1) & 3)) << 3)];
                }
                #pragma unroll
                for (int c = 0; c < 4; ++c)
                    #pragma unroll
                    for (int s = 0; s < 3; ++s)
                        acc[c][s] = __builtin_amdgcn_mfma_f32_16x16x32_bf16(a[c], b[s], acc[c][s], 0, 0, 0);
            }
            __syncthreads();
            ++sub;
        }
        if (ch + 1 < NCH) { stageB(ch + 1); __syncthreads(); }
    }

    if (MODE == 0) {
        float* out = po + (size_t)kk * ((size_t)SB * COUT * 576)
                   + ((size_t)img * COUT + cgb * 64) * 576;
        #pragma unroll
        for (int c = 0; c < 4; ++c)
            #pragma unroll
            for (int s = 0; s < 3; ++s)
                #pragma unroll
                for (int r = 0; r < 4; ++r) {
                    int col = c * 16 + quad * 4 + r;
                    out[(size_t)col * 576 + pxs[s]] = acc[c][s][r];
                }
    } else {
        #pragma unroll
        for (int c = 0; c < 4; ++c)
            #pragma unroll
            for (int s = 0; s < 3; ++s) {
                int px = pxs[s];
                #pragma unroll
                for (int r = 0; r < 4; ++r) {
                    int co = cgb * 64 + c * 16 + quad * 4 + r;
                    int which = co >> 7, cl = co & 127;
                    const float* bp = (which == 0) ? b0 : (which == 1) ? b1 : b2;
                    float v = acc[c][s][r] + bp[cl];
                    if (which == 0) {
                        t0[((size_t)img * 576 + px) * 128 + cl] = f2bf(v);
                    } else if (which == 1) {
                        int mt = px >> 4, l15m = px & 15;
                        int kb = cl >> 5, quadk = (cl >> 3) & 3, jj = cl & 7;
                        t1[(((size_t)img * 36 + mt) * 4 + kb) * 512 + (quadk * 16 + l15m) * 8 + jj] = f2bf(v);
                    } else {
                        int ctile = cl >> 4, l15v = cl & 15;
                        int sIdx = px >> 5, quadv = (px >> 3) & 3, jj = px & 7;
                        t2[(((size_t)img * 8 + ctile) * 18 + sIdx) * 512 + (quadv * 16 + l15v) * 8 + jj] = f2bf(v);
                    }
                }
            }
    }
}

template<int KD, int R, int CINT, int SPLITK, int MODE>
__global__ __launch_bounds__(256, 1) void conv_mfma(
    const unsigned short* __restrict__ srcA, const unsigned short* __restrict__ srcB,
    const unsigned short* __restrict__ Apk, int COUT, float* __restrict__ po,
    const float* __restrict__ b0, const float* __restrict__ b1, const float* __restrict__ b2,
    unsigned short* __restrict__ t0, unsigned short* __restrict__ t1,
    unsigned short* __restrict__ t2)
{
    conv_body<KD, R, CINT, SPLITK, MODE>(blockIdx.x, blockIdx.y, blockIdx.z,
        srcA, srcB, Apk, COUT, po, b0, b1, b2, t0, t1, t2);
}

// ---------------------------------------------------------------- yt (MFMA) -> K-packed
__device__ __forceinline__ void yt_body(
    int mt, int img,
    const unsigned short* __restrict__ hT, const unsigned short* __restrict__ Wcb,
    unsigned short* __restrict__ KFi)
{
    int t = threadIdx.x, wave = t >> 6, lane = t & 63;
    int q = lane >> 4, l15 = lane & 15;
    int n0 = mt * 16;
    v4f acc[2];
    #pragma unroll
    for (int ct = 0; ct < 2; ++ct)
        #pragma unroll
        for (int r = 0; r < 4; ++r) acc[ct][r] = 0.f;
    #pragma unroll
    for (int kk = 0; kk < 4; ++kk) {
        v8s b = *(const v8s*)(hT + ((size_t)img * 576 + n0 + l15) * 128 + kk * 32 + q * 8);
        #pragma unroll
        for (int ct = 0; ct < 2; ++ct) {
            v8s a = *(const v8s*)(Wcb + (size_t)((wave * 2 + ct) * 16 + l15) * 128 + kk * 32 + q * 8);
            acc[ct] = __builtin_amdgcn_mfma_f32_16x16x32_bf16(a, b, acc[ct], 0, 0, 0);
        }
    }
    #pragma unroll
    for (int ct = 0; ct < 2; ++ct) {
        #pragma unroll
        for (int r = 0; r < 4; ++r) {
            int co = (wave * 2 + ct) * 16 + q * 4 + r;
            int kk = co >> 5, quadk = (co >> 3) & 3, j = co & 7;
            KFi[(((size_t)img * 36 + mt) * 4 + kk) * 512 + (quadk * 16 + l15) * 8 + j]
                = f2bf(acc[ct][r]);
        }
    }
}

// ---------------------- merged conv3 (180 blocks) + yt (360 blocks) — both need only hT16
__global__ __launch_bounds__(256, 1) void conv3_yt_kernel(
    const unsigned short* __restrict__ hT, const unsigned short* __restrict__ Wp3,
    const float* __restrict__ Wf_b, const float* __restrict__ Wh_b,
    const float* __restrict__ Wl_b,
    unsigned short* __restrict__ ftT, unsigned short* __restrict__ KFa,
    unsigned short* __restrict__ VFa,
    const unsigned short* __restrict__ Wcb, unsigned short* __restrict__ KFi)
{
    int bid = blockIdx.x;
    if (bid < 180) {
        conv_body<3, 1, 128, 1, 1>(bid % 6, (bid / 6) % 3, bid / 18,
            hT, hT, Wp3, 384, nullptr, Wf_b, Wh_b, Wl_b, ftT, KFa, VFa);
    } else {
        int b2 = bid - 180;
        yt_body(b2 % 36, b2 / 36, hT, Wcb, KFi);
    }
}

// ---------------------------------------------------- MFMA flash attention (merged)
// 32-row Q tiles; 1D grid with bijective XCD chunk swizzle + kimg-major pair order
// (R5: keeps each kimg's K/V on 1-2 XCD L2s). Output at original pp index.
__global__ __launch_bounds__(256) void attn_merged(
    const unsigned short* __restrict__ QTi, const unsigned short* __restrict__ KFa,
    const unsigned short* __restrict__ VFa, float* __restrict__ Of,
    const float* __restrict__ addsrc, const float* __restrict__ alpha,
    const unsigned short* __restrict__ QTe, const unsigned short* __restrict__ KFe,
    const unsigned short* __restrict__ VFe, unsigned short* __restrict__ Oh,
    float* __restrict__ wpart)
{
    __shared__ __align__(16) unsigned short P[32 * 576];
    __shared__ float redmx[4][32];
    __shared__ float redsm[4][32];
    int t = threadIdx.x;
    int wave = t >> 6, lane = t & 63;
    int q = lane >> 4, l15 = lane & 15;

    // bijective swizzle over 900 = 8*112 + 4 blocks (m204 variant)
    int bid = blockIdx.x;
    int xcd = bid & 7, slot = bid >> 3;
    int gs = (xcd < 4) ? xcd * 113 + slot : 452 + (xcd - 4) * 112 + slot;
    int p = gs / 18;
    int mt2 = gs - p * 18;
    int n0 = mt2 * 32;

    bool intra = (p < SB);
    int pp = 0;
    const unsigned short *Qp, *Kp, *Vp;
    if (intra) {
        Qp = QTi + ((size_t)p * 576 + n0) * 128;
        Kp = KFa + (size_t)p * 36 * 4 * 512;
        Vp = VFa + (size_t)p * 8 * 18 * 512;
    } else {
        int pe = p - SB;                       // j-major enumeration
        int j = pe >> 3; int t2 = pe & 7;
        int b = t2 & 1;  int ii = t2 >> 1;
        int i = ii + (ii >= j ? 1 : 0);
        int qimg = i * 2 + b, kimg = j * 2 + b;
        pp = (i * 4 + (j - (j > i ? 1 : 0))) * 2 + b;  // original output index
        Qp = QTe + ((size_t)qimg * 576 + n0) * 128;
        Kp = KFe + (size_t)kimg * 36 * 4 * 512;
        Vp = VFe + (size_t)kimg * 8 * 18 * 512;
    }

    v8s aq[2][4];
    #pragma unroll
    for (int qt = 0; qt < 2; ++qt)
        #pragma unroll
        for (int kk = 0; kk < 4; ++kk)
            aq[qt][kk] = *(const v8s*)(Qp + (size_t)(qt * 16 + l15) * 128 + kk * 32 + q * 8);

    v4f S[2][9];
    #pragma unroll
    for (int qt = 0; qt < 2; ++qt)
        #pragma unroll
        for (int i = 0; i < 9; ++i)
            #pragma unroll
            for (int r = 0; r < 4; ++r) S[qt][i][r] = 0.f;

    #pragma unroll
    for (int i = 0; i < 9; ++i) {
        int mtk = wave * 9 + i;
        #pragma unroll
        for (int kk = 0; kk < 4; ++kk) {
            v8s b = *(const v8s*)(Kp + ((size_t)(mtk * 4 + kk)) * 512 + lane * 8);
            S[0][i] = __builtin_amdgcn_mfma_f32_16x16x32_bf16(aq[0][kk], b, S[0][i], 0, 0, 0);
            S[1][i] = __builtin_amdgcn_mfma_f32_16x16x32_bf16(aq[1][kk], b, S[1][i], 0, 0, 0);
        }
    }

    #pragma unroll
    for (int qt = 0; qt < 2; ++qt) {
        #pragma unroll
        for (int r = 0; r < 4; ++r) {
            float m = S[qt][0][r];
            #pragma unroll
            for (int i = 1; i < 9; ++i) m = fmaxf(m, S[qt][i][r]);
            #pragma unroll
            for (int off = 1; off < 16; off <<= 1) m = fmaxf(m, __shfl_xor(m, off));
            if (l15 == 0) redmx[wave][qt * 16 + q * 4 + r] = m;
        }
    }
    __syncthreads();
    float sum[2][4];
    #pragma unroll
    for (int qt = 0; qt < 2; ++qt) {
        #pragma unroll
        for (int r = 0; r < 4; ++r) {
            int rr = qt * 16 + q * 4 + r;
            float g = fmaxf(fmaxf(redmx[0][rr], redmx[1][rr]),
                            fmaxf(redmx[2][rr], redmx[3][rr]));
            float s = 0.f;
            #pragma unroll
            for (int i = 0; i < 9; ++i) { float e = __expf(S[qt][i][r] - g); S[qt][i][r] = e; s += e; }
            #pragma unroll
            for (int off = 1; off < 16; off <<= 1) s += __shfl_xor(s, off);
            sum[qt][r] = s;
        }
    }
    if (l15 == 0) {
        #pragma unroll
        for (int qt = 0; qt < 2; ++qt)
            #pragma unroll
            for (int r = 0; r < 4; ++r) redsm[wave][qt * 16 + q * 4 + r] = sum[qt][r];
    }
    #pragma unroll
    for (int qt = 0; qt < 2; ++qt) {
        #pragma unroll
        for (int i = 0; i < 9; ++i) {
            int m = (wave * 9 + i) * 16 + l15;
            int cm = m >> 3, mo = m & 7;
            #pragma unroll
            for (int r = 0; r < 4; ++r) {
                int n = qt * 16 + q * 4 + r;
                P[n * 576 + ((cm ^ (n & 7)) << 3) + mo] = f2bf(S[qt][i][r]);
            }
        }
    }
    __syncthreads();
    float inv[2][4];
    #pragma unroll
    for (int qt = 0; qt < 2; ++qt)
        #pragma unroll
        for (int r = 0; r < 4; ++r) {
            int rr = qt * 16 + q * 4 + r;
            inv[qt][r] = 1.f / (redsm[0][rr] + redsm[1][rr] + redsm[2][rr] + redsm[3][rr]);
        }

    v4f o[2][2];
    #pragma unroll
    for (int qt = 0; qt < 2; ++qt)
        #pragma unroll
        for (int ct = 0; ct < 2; ++ct)
            #pragma unroll
            for (int r = 0; r < 4; ++r) o[qt][ct][r] = 0.f;

    for (int s = 0; s < 18; ++s) {
        int cm = s * 4 + q;
        v8s a0 = *(const v8s*)&P[l15 * 576 + ((cm ^ (l15 & 7)) << 3)];
        v8s a1 = *(const v8s*)&P[(16 + l15) * 576 + ((cm ^ (l15 & 7)) << 3)];
        #pragma unroll
        for (int ct = 0; ct < 2; ++ct) {
            int ctile = wave * 2 + ct;
            v8s b = *(const v8s*)(Vp + ((size_t)(ctile * 18 + s)) * 512 + lane * 8);
            o[0][ct] = __builtin_amdgcn_mfma_f32_16x16x32_bf16(a0, b, o[0][ct], 0, 0, 0);
            o[1][ct] = __builtin_amdgcn_mfma_f32_16x16x32_bf16(a1, b, o[1][ct], 0, 0, 0);
        }
    }

    if (intra) {
        float al = alpha[0];
        #pragma unroll
        for (int qt = 0; qt < 2; ++qt)
            #pragma unroll
            for (int ct = 0; ct < 2; ++ct) {
                int c = (wave * 2 + ct) * 16 + l15;
                size_t base = ((size_t)p * 128 + c) * 576 + n0 + qt * 16 + q * 4;
                #pragma unroll
                for (int r = 0; r < 4; ++r)
                    Of[base + r] = al * o[qt][ct][r] * inv[qt][r] + addsrc[base + r];
            }
    } else {
        #pragma unroll
        for (int ct = 0; ct < 2; ++ct) {
            int c = (wave * 2 + ct) * 16 + l15;
            float sums[9];
            #pragma unroll
            for (int k = 0; k < 9; ++k) sums[k] = 0.f;
            #pragma unroll
            for (int qt = 0; qt < 2; ++qt) {
                size_t base = ((size_t)pp * 128 + c) * 576 + n0 + qt * 16 + q * 4;
                #pragma unroll
                for (int r = 0; r < 4; ++r) {
                    unsigned short hb = f2bf(o[qt][ct][r] * inv[qt][r]);
                    Oh[base + r] = hb;
                    float v = bf2f(hb);
                    int px = n0 + qt * 16 + q * 4 + r;
                    int row = px / 24, col = px % 24;
                    sums[0] += v;
                    if (row == 0)  sums[1] += v;
                    if (row == 23) sums[2] += v;
                    if (col == 0)  sums[3] += v;
                    if (col == 23) sums[4] += v;
                    if (px == 0)   sums[5] += v;
                    if (px == 23)  sums[6] += v;
                    if (px == 552) sums[7] += v;
                    if (px == 575) sums[8] += v;
                }
            }
            #pragma unroll
            for (int k = 0; k < 9; ++k) {
                sums[k] += __shfl_xor(sums[k], 16);
                sums[k] += __shfl_xor(sums[k], 32);
            }
            if (q == 0) {
                float* wp = wpart + (((size_t)pp * 18 + mt2) * 9) * 128 + c;
                #pragma unroll
                for (int k = 0; k < 9; ++k) wp[k * 128] = sums[k];
            }
        }
    }
}

// gate: reduce per-mt2 partials (L2-resident), 4-way split dot via WgT (512 thr:
// 4 groups x 128 co — halves the serial dot chain vs 2-way; R9)
__global__ __launch_bounds__(512) void g_kernel(
    const float* __restrict__ wpart, const float* __restrict__ WgT,
    const float* __restrict__ Wgb, float* __restrict__ g)
{
    __shared__ float sw[C_ * 9];
    __shared__ float swp[3][C_ * 9];
    __shared__ float acc2[512];
    int pair = blockIdx.x; int t = threadIdx.x;
    int co = t & 127, grp = t >> 7;
    const float* base = wpart + (size_t)pair * 18 * 9 * 128 + co;
    float raw[9];
    #pragma unroll
    for (int k = 0; k < 9; ++k) raw[k] = 0.f;
    for (int mt = grp; mt < 18; mt += 4) {
        #pragma unroll
        for (int k = 0; k < 9; ++k) raw[k] += base[(mt * 9 + k) * 128];
    }
    if (grp > 0) {
        #pragma unroll
        for (int k = 0; k < 9; ++k) swp[grp - 1][co * 9 + k] = raw[k];
    }
    __syncthreads();
    if (grp == 0) {
        #pragma unroll
        for (int k = 0; k < 9; ++k)
            raw[k] += swp[0][co * 9 + k] + swp[1][co * 9 + k] + swp[2][co * 9 + k];
        float rowsub[3] = {raw[2], 0.f, raw[1]};
        float colsub[3] = {raw[4], 0.f, raw[3]};
        float corner[9] = {raw[8], 0.f, raw[7], 0.f, 0.f, 0.f, raw[6], 0.f, raw[5]};
        #pragma unroll
        for (int ky = 0; ky < 3; ++ky)
            #pragma unroll
            for (int kx = 0; kx < 3; ++kx)
                sw[co * 9 + ky * 3 + kx] = raw[0] - rowsub[ky] - colsub[kx] + corner[ky * 3 + kx];
    }
    __syncthreads();
    float acc = 0.f;
    const float* wg = WgT + (size_t)grp * 288 * 128 + co;
    const float* swh = sw + grp * 288;
    for (int i = 0; i < 288; ++i) acc += wg[(size_t)i * 128] * swh[i];
    acc2[t] = acc;
    __syncthreads();
    if (grp == 0) {
        float m = (acc + acc2[t + 128] + acc2[t + 256] + acc2[t + 384]) * (1.f / 576.f) + Wgb[co];
        g[pair * C_ + co] = 1.f / (1.f + __expf(-m));
    }
}

// ----------------------- fused msg compute + transpose-cast -> msgT16 [px][c]
__global__ __launch_bounds__(256) void msg_tc_kernel(
    const float* __restrict__ eii, const unsigned short* __restrict__ mji,
    const float* __restrict__ g, const float* __restrict__ bn_gamma,
    const float* __restrict__ bn_beta, const float* __restrict__ intra_w,
    const float* __restrict__ inter_w, unsigned short* __restrict__ msgT)
{
    __shared__ float tile[128][9];
    int img = blockIdx.y, px0 = blockIdx.x * 8, t = threadIdx.x;
    int s = img >> 1, b = img & 1;
    float iw = intra_w[0], ew = inter_w[0];
    #pragma unroll
    for (int i = 0; i < 4; ++i) {
        int e = i * 256 + t; int ci = e >> 3; int pxl = e & 7;
        int px = px0 + pxl;
        float scale = bn_gamma[ci] * rsqrtf(1.f + 1e-5f);
        float acc = 0.f;
        #pragma unroll
        for (int jj = 0; jj < 4; ++jj) {
            int pidx = (s * 4 + jj) * 2 + b;
            acc += g[pidx * C_ + ci] * bf2f(mji[((size_t)pidx * C_ + ci) * N_ + px]);
        }
        float inter = scale * acc + 4.f * bn_beta[ci];
        tile[ci][pxl] = iw * eii[((size_t)img * C_ + ci) * N_ + px] + ew * inter;
    }
    __syncthreads();
    #pragma unroll
    for (int i = 0; i < 4; ++i) {
        int e = i * 256 + t; int pxl = e >> 7; int ci = e & 127;
        msgT[((size_t)img * 576 + px0 + pxl) * 128 + ci] = f2bf(tile[ci][pxl]);
    }
}

// -------- fused GRU update + next-iter transpose/packs (hT [px][c], VF pack)
__global__ __launch_bounds__(256) void update_tc_kernel(
    const float* __restrict__ zrp, const float* __restrict__ zrb,
    const float* __restrict__ hhp, const float* __restrict__ ghb,
    const float* __restrict__ h, float* __restrict__ out,
    unsigned short* __restrict__ hTn, unsigned short* __restrict__ VFn, int last)
{
    const size_t ZP = (size_t)SB * C2 * N_;
    const size_t HP = (size_t)SB * C_ * N_;
    __shared__ float tile[128][9];
    int img = blockIdx.y, px0 = blockIdx.x * 8, t = threadIdx.x;
    #pragma unroll
    for (int i = 0; i < 4; ++i) {
        int e = i * 256 + t; int ci = e >> 3; int pxl = e & 7;
        int px = px0 + pxl;
        size_t zi = ((size_t)img * C2 + ci) * N_ + px;
        float za = zrb[ci];
        #pragma unroll
        for (int k = 0; k < ZRSPLIT; ++k) za += zrp[k * ZP + zi];
        float z = 1.f / (1.f + __expf(-za));
        size_t hi = ((size_t)img * C_ + ci) * N_ + px;
        float ha = ghb[ci];
        #pragma unroll
        for (int k = 0; k < 4; ++k) ha += hhp[k * HP + hi];
        float hh = tanhf(ha);
        float o = (2.f - z) * h[hi] + z * hh;
        out[hi] = o;
        tile[ci][pxl] = o;
        if (!last) {
            int ctile = ci >> 4, l15v = ci & 15;
            int sIdx = px >> 5, quadv = (px >> 3) & 3, j = px & 7;
            VFn[(((size_t)img * 8 + ctile) * 18 + sIdx) * 512 + (quadv * 16 + l15v) * 8 + j] = f2bf(o);
        }
    }
    if (!last) {
        __syncthreads();
        #pragma unroll
        for (int i = 0; i < 4; ++i) {
            int e = i * 256 + t; int pxl = e >> 7; int ci = e & 127;
            hTn[((size_t)img * 576 + px0 + pxl) * 128 + ci] = f2bf(tile[ci][pxl]);
        }
    }
}

// ------------------------------------------------------------------- launcher
extern "C" void kernel_launch(void* const* d_in, const int* in_sizes, int n_in,
                              void* d_out, int out_size, void* d_ws, size_t ws_size,
                              hipStream_t stream)
{
    const float* x      = (const float*)d_in[0];
    const float* Wf_w   = (const float*)d_in[1];
    const float* Wf_b   = (const float*)d_in[2];
    const float* Wh_w   = (const float*)d_in[3];
    const float* Wh_b   = (const float*)d_in[4];
    const float* Wl_w   = (const float*)d_in[5];
    const float* Wl_b   = (const float*)d_in[6];
    const float* alpha  = (const float*)d_in[7];
    const float* Wc     = (const float*)d_in[8];
    const float* Wg_w   = (const float*)d_in[9];
    const float* Wg_b   = (const float*)d_in[10];
    const float* bng    = (const float*)d_in[11];
    const float* bnb    = (const float*)d_in[12];
    const float* zr_w   = (const float*)d_in[13];
    const float* zr_b   = (const float*)d_in[14];
    const float* gh_w   = (const float*)d_in[15];
    const float* gh_b   = (const float*)d_in[16];
    const float* intraw = (const float*)d_in[17];
    const float* interw = (const float*)d_in[18];
    float* outp = (float*)d_out;

    float* f = (float*)d_ws;
    const size_t SZ = (size_t)SB * C_ * N_;
    float* hbuf  = f; f += SZ;
    float* eii   = f; f += SZ;
    float* zrp   = f; f += (size_t)ZRSPLIT * SB * C2 * N_;
    float* hhp   = f; f += 4 * SZ;
    float* wpart = f; f += (size_t)NPAIR * 18 * 9 * 128;
    float* gbuf  = f; f += (size_t)NPAIR * C_;
    float* WgT   = f; f += (size_t)128 * 1152;
    unsigned short* us = (unsigned short*)f;
    unsigned short* mji16  = us; us += (size_t)NPAIR * C_ * N_;
    unsigned short* hT16   = us; us += SZ;
    unsigned short* hc16   = us; us += SZ;           // VFi inter / rhbT16
    unsigned short* msgT16 = us; us += SZ;
    unsigned short* ftT    = us; us += SZ;           // Q intra
    unsigned short* KFa    = us; us += SZ;
    unsigned short* VFa    = us; us += SZ;
    unsigned short* Wp3    = us; us += (size_t)384 * 1152;
    unsigned short* Wpzr   = us; us += (size_t)256 * 6400;
    unsigned short* Wph    = us; us += (size_t)128 * 6400;
    unsigned short* Wcb    = us; us += (size_t)128 * 128;
    unsigned short* KFi    = us; us += SZ;

    unsigned short* VFi    = hc16;
    unsigned short* rhbT16 = hc16;

    // all weight packs + initial transpose/pack of x in ONE launch
    pack_all_kernel<<<NB_A3 + NB_A5ZR + NB_A5H + NB_WC + NB_WGT + NB_TC, 256, 0, stream>>>(
        Wf_w, Wh_w, Wl_w, Wp3, zr_w, Wpzr, gh_w, Wph, Wc, Wcb, Wg_w, WgT,
        x, hT16, VFi);

    const float* hcur = x;
    for (int it = 0; it < 3; ++it) {
        float* hout = (it == 2) ? outp : hbuf;

        conv3_yt_kernel<<<540, 256, 0, stream>>>(
            hT16, Wp3, Wf_b, Wh_b, Wl_b, ftT, KFa, VFa, Wcb, KFi);
        attn_merged<<<900, 256, 0, stream>>>(
            ftT, KFa, VFa, eii, hcur, alpha, hT16, KFi, VFi, mji16, wpart);
        g_kernel<<<NPAIR, 512, 0, stream>>>(wpart, WgT, Wg_b, gbuf);
        msg_tc_kernel<<<dim3(72, SB), 256, 0, stream>>>(
            eii, mji16, gbuf, bng, bnb, intraw, interw, msgT16);
        conv_mfma<5, 2, 256, ZRSPLIT, 0><<<dim3(4 * ZRSPLIT, 3, SB), 256, 0, stream>>>(
            msgT16, hT16, Wpzr, 256, zrp, nullptr, nullptr, nullptr, nullptr, nullptr, nullptr);
        tc_kernel<<<dim3(72, SB), 256, 0, stream>>>(hcur, zrp, zr_b, rhbT16, nullptr);
        conv_mfma<5, 2, 256, 4, 0><<<dim3(8, 3, SB), 256, 0, stream>>>(
            msgT16, rhbT16, Wph, 128, hhp, nullptr, nullptr, nullptr, nullptr, nullptr, nullptr);
        update_tc_kernel<<<dim3(72, SB), 256, 0, stream>>>(
            zrp, zr_b, hhp, gh_b, hcur, hout, hT16, VFi, (it == 2) ? 1 : 0);
        hcur = hout;
    }
}

// Round 10
// 498.450 us; speedup vs baseline: 1.0810x; 1.0077x over previous
//
#include <hip/hip_runtime.h>
#include <math.h>

#define S_  5
#define B_  2
#define C_  128
#define N_  576
#define SB  10
#define NPAIR 40
#define C2  256
#define ZRSPLIT 4   // R8 lesson: conv5 needs 480 blocks (2/CU) to hide barrier drains

typedef short v8s __attribute__((ext_vector_type(8)));
typedef float v4f __attribute__((ext_vector_type(4)));

#define GLOBAL_AS __attribute__((address_space(1)))
#define LDS_AS    __attribute__((address_space(3)))

__device__ __forceinline__ unsigned short f2bf(float f) {
    union { float f; unsigned u; } v; v.f = f;
    unsigned r = (v.u + 0x7FFF + ((v.u >> 16) & 1)) >> 16;
    return (unsigned short)r;
}
__device__ __forceinline__ float bf2f(unsigned short h) {
    union { unsigned u; float f; } v; v.u = ((unsigned)h) << 16;
    return v.f;
}

// ------------------------------------------------------------------ weight pack bodies
// Fragment-major A: [cgb][kk][ch][g][tap_l][c(4)][l15(16)][quad(4)][j(8)]
__device__ __forceinline__ void packA5_body(int idx, const float* __restrict__ w,
                                            unsigned short* __restrict__ Apk, int M)
{
    if (idx >= M * 6400) return;
    int r = idx;
    int j = r & 7;      r >>= 3;
    int quad = r & 3;   r >>= 2;
    int l15 = r & 15;   r >>= 4;
    int c = r & 3;      r >>= 2;
    int tap_l = r % 5;  r /= 5;
    int g = r % 5;      r /= 5;
    int ch = r & 1;     r >>= 1;
    int kk = r & 3;     r >>= 2;
    int cgb = r;
    int co = cgb * 64 + c * 16 + l15;
    int ci = kk * 64 + ch * 32 + quad * 8 + j;
    int tap = g * 5 + tap_l;
    Apk[idx] = f2bf(w[((size_t)co * 256 + ci) * 25 + tap]);
}
__device__ __forceinline__ void packA3_body(int idx, const float* __restrict__ wf,
                                            const float* __restrict__ wh,
                                            const float* __restrict__ wl,
                                            unsigned short* __restrict__ Apk)
{
    if (idx >= 384 * 1152) return;
    int r = idx;
    int j = r & 7;      r >>= 3;
    int quad = r & 3;   r >>= 2;
    int l15 = r & 15;   r >>= 4;
    int c = r & 3;      r >>= 2;
    int tap_l = r % 3;  r /= 3;
    int g = r % 3;      r /= 3;
    int ch = r & 1;     r >>= 1;
    int kk = r & 1;     r >>= 1;
    int cgb = r;
    int co = cgb * 64 + c * 16 + l15;
    const float* w = (co < 128) ? wf : (co < 256) ? wh : wl;
    int cl = co & 127;
    int ci = kk * 64 + ch * 32 + quad * 8 + j;
    int tap = g * 3 + tap_l;
    Apk[idx] = f2bf(w[((size_t)cl * 128 + ci) * 9 + tap]);
}
__device__ __forceinline__ void packWc_body(int idx, const float* __restrict__ w,
                                            unsigned short* __restrict__ o)
{
    if (idx < 128 * 128) o[idx] = f2bf(w[idx]);
}
// Wg[co][i] -> WgT[i][co]  (coalesced g_kernel reads)
__device__ __forceinline__ void packWgT_body(int idx, const float* __restrict__ w,
                                             float* __restrict__ o)
{
    if (idx >= 128 * 1152) return;
    int co = idx & 127, i = idx >> 7;
    o[(size_t)i * 128 + co] = w[(size_t)co * 1152 + i];
}

// ---------------------------------------------- transpose-cast body (x at it=0, rhb)
__device__ __forceinline__ void tc_body(
    int px0, int img,
    const float* __restrict__ src, const float* __restrict__ zrp,
    const float* __restrict__ zrb,
    unsigned short* __restrict__ dst, unsigned short* __restrict__ vfd)
{
    const size_t PLANE = (size_t)SB * C2 * N_;
    __shared__ float tile[128][9];
    int t = threadIdx.x;
    #pragma unroll
    for (int i = 0; i < 4; ++i) {
        int e = i * 256 + t; int ci = e >> 3; int px = e & 7;
        float v = src[((size_t)img * 128 + ci) * 576 + px0 + px];
        if (zrp) {
            size_t zi = ((size_t)img * C2 + 128 + ci) * 576 + px0 + px;
            float a = zrb[128 + ci];
            #pragma unroll
            for (int k = 0; k < ZRSPLIT; ++k) a += zrp[k * PLANE + zi];
            v *= 1.f / (1.f + __expf(-a));
        }
        tile[ci][px] = v;
        if (vfd) {
            int m = px0 + px;
            int ctile = ci >> 4, l15v = ci & 15;
            int sIdx = m >> 5, quadv = (m >> 3) & 3, j = m & 7;
            vfd[(((size_t)img * 8 + ctile) * 18 + sIdx) * 512 + (quadv * 16 + l15v) * 8 + j] = f2bf(v);
        }
    }
    __syncthreads();
    #pragma unroll
    for (int i = 0; i < 4; ++i) {
        int e = i * 256 + t; int pxl = e >> 7; int ci = e & 127;
        dst[((size_t)img * 576 + px0 + pxl) * 128 + ci] = f2bf(tile[ci][pxl]);
    }
}

// loop-phase tc (rhb path) stays a standalone kernel
__global__ __launch_bounds__(256) void tc_kernel(
    const float* __restrict__ src, const float* __restrict__ zrp,
    const float* __restrict__ zrb,
    unsigned short* __restrict__ dst, unsigned short* __restrict__ vfd)
{
    tc_body(blockIdx.x * 8, blockIdx.y, src, zrp, zrb, dst, vfd);
}

// ----------------------------------------- merged setup: all packs + initial tc
// pack bodies: 4 elements/thread (1024/block) — 4x MLP per thread, 1/4 the blocks
#define NB_A3   432
#define NB_A5ZR 1600
#define NB_A5H  800
#define NB_WC   16
#define NB_WGT  144
#define NB_TC   720
__global__ __launch_bounds__(256) void pack_all_kernel(
    const float* __restrict__ Wf_w, const float* __restrict__ Wh_w,
    const float* __restrict__ Wl_w, unsigned short* __restrict__ Wp3,
    const float* __restrict__ zr_w, unsigned short* __restrict__ Wpzr,
    const float* __restrict__ gh_w, unsigned short* __restrict__ Wph,
    const float* __restrict__ Wc,  unsigned short* __restrict__ Wcb,
    const float* __restrict__ Wg_w, float* __restrict__ WgT,
    const float* __restrict__ x, unsigned short* __restrict__ hT16,
    unsigned short* __restrict__ VFi)
{
    int bid = blockIdx.x, t = threadIdx.x;
    if (bid < NB_A3) {
        int base = bid * 1024 + t;
        #pragma unroll
        for (int k = 0; k < 4; ++k) packA3_body(base + k * 256, Wf_w, Wh_w, Wl_w, Wp3);
    } else if (bid < NB_A3 + NB_A5ZR) {
        int base = (bid - NB_A3) * 1024 + t;
        #pragma unroll
        for (int k = 0; k < 4; ++k) packA5_body(base + k * 256, zr_w, Wpzr, 256);
    } else if (bid < NB_A3 + NB_A5ZR + NB_A5H) {
        int base = (bid - NB_A3 - NB_A5ZR) * 1024 + t;
        #pragma unroll
        for (int k = 0; k < 4; ++k) packA5_body(base + k * 256, gh_w, Wph, 128);
    } else if (bid < NB_A3 + NB_A5ZR + NB_A5H + NB_WC) {
        int base = (bid - NB_A3 - NB_A5ZR - NB_A5H) * 1024 + t;
        #pragma unroll
        for (int k = 0; k < 4; ++k) packWc_body(base + k * 256, Wc, Wcb);
    } else if (bid < NB_A3 + NB_A5ZR + NB_A5H + NB_WC + NB_WGT) {
        int base = (bid - NB_A3 - NB_A5ZR - NB_A5H - NB_WC) * 1024 + t;
        #pragma unroll
        for (int k = 0; k < 4; ++k) packWgT_body(base + k * 256, Wg_w, WgT);
    } else {
        int b2 = bid - (NB_A3 + NB_A5ZR + NB_A5H + NB_WC + NB_WGT);
        tc_body((b2 % 72) * 8, b2 / 72, x, nullptr, nullptr, hT16, VFi);
    }
}

// ------------------------------------------------------ MFMA implicit-GEMM conv v7 (R3)
// MODE 0: f32 partial planes per kk (5x5 convs, SPLITK=4)
// MODE 1: conv3 full-K fused epilogue: +bias, write ftT(Q) / KFa(K-pack) / VFa(V-pack)
// Capacity law (R6+R8): conv5 needs BOTH 2 blocks/CU (hide per-sub barrier drains)
// AND grid <= 512 (one resident round). SPLITK=4 @ 480 blocks is the unique fit.
template<int KD, int R, int CINT, int SPLITK, int MODE>
__device__ __forceinline__ void conv_body(
    int bx, int by, int bz,
    const unsigned short* __restrict__ srcA, const unsigned short* __restrict__ srcB,
    const unsigned short* __restrict__ Apk, int COUT, float* __restrict__ po,
    const float* __restrict__ b0, const float* __restrict__ b1, const float* __restrict__ b2,
    unsigned short* __restrict__ t0, unsigned short* __restrict__ t1,
    unsigned short* __restrict__ t2)
{
    constexpr int PART   = CINT / SPLITK;
    constexpr int NCH    = PART / 32;
    constexpr int NSUB   = NCH * KD;
    constexpr int WR     = 8 + 2 * R;
    constexpr int WC     = 24 + 2 * R;
    constexpr int NPOS   = WR * WC;
    constexpr int NSLOTB = NPOS * 4;
    constexpr int RB     = (NSLOTB + 255) / 256;
    constexpr int AUNITS = KD * 4 * 64;
    constexpr int AR     = AUNITS / 256;
    __shared__ __align__(16) unsigned short Ab[2][AUNITS * 8];
    __shared__ __align__(16) unsigned short Bb[NPOS * 32];

    int f   = bx;
    int kk  = f % SPLITK;
    int cgb = f / SPLITK;
    int pxb = by;
    int img = bz;
    int t = threadIdx.x;
    int wave = t >> 6, lane = t & 63;
    int quad = lane >> 4, l15 = lane & 15;
    int r0 = pxb * 8;

    const int cibase = kk * PART;
    const unsigned short* src = (cibase >= 128) ? srcB : srcA;
    const int cioff0 = cibase & 127;
    const unsigned short* srcI = src + (size_t)img * 576 * 128;

    int posBase[3], pxs[3];
    #pragma unroll
    for (int s = 0; s < 3; ++s) {
        int px = pxb * 192 + wave * 48 + s * 16 + l15;
        pxs[s] = px;
        int pr = px / 24, pc = px % 24;
        posBase[s] = (pr - r0 + R) * WC + pc + R;
    }

    int goffB[RB]; bool gokB[RB];
    #pragma unroll
    for (int rr = 0; rr < RB; ++rr) {
        int idx = rr * 256 + wave * 64 + lane;
        int pos = idx >> 2, slotq = idx & 3;
        int gr = slotq ^ ((pos >> 1) & 3);
        int wr = pos / WC, wc = pos % WC;
        int grow = r0 - R + wr, gcol = wc - R;
        gokB[rr] = (idx < NSLOTB) && grow >= 0 && grow < 24 && gcol >= 0 && gcol < 24;
        goffB[rr] = (grow * 24 + gcol) * 128 + gr * 8;
    }

    auto stageB = [&](int ch) {
        const unsigned short* sp = srcI + cioff0 + ch * 32;
        #pragma unroll
        for (int rr = 0; rr < RB; ++rr) {
            if (gokB[rr]) {
                __builtin_amdgcn_global_load_lds(
                    (const GLOBAL_AS void*)(sp + goffB[rr]),
                    (LDS_AS void*)((char*)&Bb[0] + (size_t)(rr * 256 + wave * 64) * 16),
                    16, 0, 0);
            }
        }
    };
    auto stageA = [&](int sub, int buf) {
        const unsigned short* sp = Apk + ((size_t)((cgb * SPLITK + kk) * NSUB + sub)) * (AUNITS * 8);
        #pragma unroll
        for (int r = 0; r < AR; ++r) {
            int u0 = r * 256 + wave * 64;
            __builtin_amdgcn_global_load_lds(
                (const GLOBAL_AS void*)(sp + (size_t)(u0 + lane) * 8),
                (LDS_AS void*)((char*)&Ab[buf][0] + (size_t)u0 * 16),
                16, 0, 0);
        }
    };

    v4f acc[4][3];
    #pragma unroll
    for (int c = 0; c < 4; ++c)
        #pragma unroll
        for (int s = 0; s < 3; ++s)
            #pragma unroll
            for (int r = 0; r < 4; ++r) acc[c][s][r] = 0.f;

    {
        v8s zv;
        #pragma unroll
        for (int j = 0; j < 8; ++j) zv[j] = 0;
        for (int i = t; i < NPOS * 4; i += 256) ((v8s*)Bb)[i] = zv;
    }
    __syncthreads();
    stageB(0);
    stageA(0, 0);
    __syncthreads();

    int sub = 0;
    #pragma unroll 1
    for (int ch = 0; ch < NCH; ++ch) {
        #pragma unroll 1
        for (int g = 0; g < KD; ++g) {
            if (sub + 1 < NSUB) stageA(sub + 1, (sub + 1) & 1);
            const unsigned short* Ap = &Ab[sub & 1][0];
            #pragma unroll
            for (int tl = 0; tl < KD; ++tl) {
                int doff = (g - R) * WC + (tl - R);
                v8s a[4];
                #pragma unroll
                for (int c = 0; c < 4; ++c)
                    a[c] = *(const v8s*)&Ap[((tl * 4 + c) * 64 + l15 * 4 + quad) * 8];
                v8s b[3];
                #pragma unroll
                for (int s = 0; s < 3; ++s) {
                    int pos = posBase[s] + doff;
                    b[s] = *(const v8s*)&Bb[pos * 32 + ((quad ^ ((pos >> 1) & 3)) << 3)];
                }
                #pragma unroll
                for (int c = 0; c < 4; ++c)
                    #pragma unroll
                    for (int s = 0; s < 3; ++s)
                        acc[c][s] = __builtin_amdgcn_mfma_f32_16x16x32_bf16(a[c], b[s], acc[c][s], 0, 0, 0);
            }
            __syncthreads();
            ++sub;
        }
        if (ch + 1 < NCH) { stageB(ch + 1); __syncthreads(); }
    }

    if (MODE == 0) {
        float* out = po + (size_t)kk * ((size_t)SB * COUT * 576)
                   + ((size_t)img * COUT + cgb * 64) * 576;
        #pragma unroll
        for (int c = 0; c < 4; ++c)
            #pragma unroll
            for (int s = 0; s < 3; ++s)
                #pragma unroll
                for (int r = 0; r < 4; ++r) {
                    int col = c * 16 + quad * 4 + r;
                    out[(size_t)col * 576 + pxs[s]] = acc[c][s][r];
                }
    } else {
        #pragma unroll
        for (int c = 0; c < 4; ++c)
            #pragma unroll
            for (int s = 0; s < 3; ++s) {
                int px = pxs[s];
                #pragma unroll
                for (int r = 0; r < 4; ++r) {
                    int co = cgb * 64 + c * 16 + quad * 4 + r;
                    int which = co >> 7, cl = co & 127;
                    const float* bp = (which == 0) ? b0 : (which == 1) ? b1 : b2;
                    float v = acc[c][s][r] + bp[cl];
                    if (which == 0) {
                        t0[((size_t)img * 576 + px) * 128 + cl] = f2bf(v);
                    } else if (which == 1) {
                        int mt = px >> 4, l15m = px & 15;
                        int kb = cl >> 5, quadk = (cl >> 3) & 3, jj = cl & 7;
                        t1[(((size_t)img * 36 + mt) * 4 + kb) * 512 + (quadk * 16 + l15m) * 8 + jj] = f2bf(v);
                    } else {
                        int ctile = cl >> 4, l15v = cl & 15;
                        int sIdx = px >> 5, quadv = (px >> 3) & 3, jj = px & 7;
                        t2[(((size_t)img * 8 + ctile) * 18 + sIdx) * 512 + (quadv * 16 + l15v) * 8 + jj] = f2bf(v);
                    }
                }
            }
    }
}

template<int KD, int R, int CINT, int SPLITK, int MODE>
__global__ __launch_bounds__(256, 1) void conv_mfma(
    const unsigned short* __restrict__ srcA, const unsigned short* __restrict__ srcB,
    const unsigned short* __restrict__ Apk, int COUT, float* __restrict__ po,
    const float* __restrict__ b0, const float* __restrict__ b1, const float* __restrict__ b2,
    unsigned short* __restrict__ t0, unsigned short* __restrict__ t1,
    unsigned short* __restrict__ t2)
{
    conv_body<KD, R, CINT, SPLITK, MODE>(blockIdx.x, blockIdx.y, blockIdx.z,
        srcA, srcB, Apk, COUT, po, b0, b1, b2, t0, t1, t2);
}

// ---------------------------------------------------------------- yt (MFMA) -> K-packed
__device__ __forceinline__ void yt_body(
    int mt, int img,
    const unsigned short* __restrict__ hT, const unsigned short* __restrict__ Wcb,
    unsigned short* __restrict__ KFi)
{
    int t = threadIdx.x, wave = t >> 6, lane = t & 63;
    int q = lane >> 4, l15 = lane & 15;
    int n0 = mt * 16;
    v4f acc[2];
    #pragma unroll
    for (int ct = 0; ct < 2; ++ct)
        #pragma unroll
        for (int r = 0; r < 4; ++r) acc[ct][r] = 0.f;
    #pragma unroll
    for (int kk = 0; kk < 4; ++kk) {
        v8s b = *(const v8s*)(hT + ((size_t)img * 576 + n0 + l15) * 128 + kk * 32 + q * 8);
        #pragma unroll
        for (int ct = 0; ct < 2; ++ct) {
            v8s a = *(const v8s*)(Wcb + (size_t)((wave * 2 + ct) * 16 + l15) * 128 + kk * 32 + q * 8);
            acc[ct] = __builtin_amdgcn_mfma_f32_16x16x32_bf16(a, b, acc[ct], 0, 0, 0);
        }
    }
    #pragma unroll
    for (int ct = 0; ct < 2; ++ct) {
        #pragma unroll
        for (int r = 0; r < 4; ++r) {
            int co = (wave * 2 + ct) * 16 + q * 4 + r;
            int kk = co >> 5, quadk = (co >> 3) & 3, j = co & 7;
            KFi[(((size_t)img * 36 + mt) * 4 + kk) * 512 + (quadk * 16 + l15) * 8 + j]
                = f2bf(acc[ct][r]);
        }
    }
}

// ---------------------- merged conv3 (180 blocks) + yt (360 blocks) — both need only hT16
__global__ __launch_bounds__(256, 1) void conv3_yt_kernel(
    const unsigned short* __restrict__ hT, const unsigned short* __restrict__ Wp3,
    const float* __restrict__ Wf_b, const float* __restrict__ Wh_b,
    const float* __restrict__ Wl_b,
    unsigned short* __restrict__ ftT, unsigned short* __restrict__ KFa,
    unsigned short* __restrict__ VFa,
    const unsigned short* __restrict__ Wcb, unsigned short* __restrict__ KFi)
{
    int bid = blockIdx.x;
    if (bid < 180) {
        conv_body<3, 1, 128, 1, 1>(bid % 6, (bid / 6) % 3, bid / 18,
            hT, hT, Wp3, 384, nullptr, Wf_b, Wh_b, Wl_b, ftT, KFa, VFa);
    } else {
        int b2 = bid - 180;
        yt_body(b2 % 36, b2 / 36, hT, Wcb, KFi);
    }
}

// ---------------------------------------------------- MFMA flash attention (merged)
// 32-row Q tiles; 1D grid with bijective XCD chunk swizzle + kimg-major pair order
// (R5: keeps each kimg's K/V on 1-2 XCD L2s). Output at original pp index.
__global__ __launch_bounds__(256) void attn_merged(
    const unsigned short* __restrict__ QTi, const unsigned short* __restrict__ KFa,
    const unsigned short* __restrict__ VFa, float* __restrict__ Of,
    const float* __restrict__ addsrc, const float* __restrict__ alpha,
    const unsigned short* __restrict__ QTe, const unsigned short* __restrict__ KFe,
    const unsigned short* __restrict__ VFe, unsigned short* __restrict__ Oh,
    float* __restrict__ wpart)
{
    __shared__ __align__(16) unsigned short P[32 * 576];
    __shared__ float redmx[4][32];
    __shared__ float redsm[4][32];
    int t = threadIdx.x;
    int wave = t >> 6, lane = t & 63;
    int q = lane >> 4, l15 = lane & 15;

    // bijective swizzle over 900 = 8*112 + 4 blocks (m204 variant)
    int bid = blockIdx.x;
    int xcd = bid & 7, slot = bid >> 3;
    int gs = (xcd < 4) ? xcd * 113 + slot : 452 + (xcd - 4) * 112 + slot;
    int p = gs / 18;
    int mt2 = gs - p * 18;
    int n0 = mt2 * 32;

    bool intra = (p < SB);
    int pp = 0;
    const unsigned short *Qp, *Kp, *Vp;
    if (intra) {
        Qp = QTi + ((size_t)p * 576 + n0) * 128;
        Kp = KFa + (size_t)p * 36 * 4 * 512;
        Vp = VFa + (size_t)p * 8 * 18 * 512;
    } else {
        int pe = p - SB;                       // j-major enumeration
        int j = pe >> 3; int t2 = pe & 7;
        int b = t2 & 1;  int ii = t2 >> 1;
        int i = ii + (ii >= j ? 1 : 0);
        int qimg = i * 2 + b, kimg = j * 2 + b;
        pp = (i * 4 + (j - (j > i ? 1 : 0))) * 2 + b;  // original output index
        Qp = QTe + ((size_t)qimg * 576 + n0) * 128;
        Kp = KFe + (size_t)kimg * 36 * 4 * 512;
        Vp = VFe + (size_t)kimg * 8 * 18 * 512;
    }

    v8s aq[2][4];
    #pragma unroll
    for (int qt = 0; qt < 2; ++qt)
        #pragma unroll
        for (int kk = 0; kk < 4; ++kk)
            aq[qt][kk] = *(const v8s*)(Qp + (size_t)(qt * 16 + l15) * 128 + kk * 32 + q * 8);

    v4f S[2][9];
    #pragma unroll
    for (int qt = 0; qt < 2; ++qt)
        #pragma unroll
        for (int i = 0; i < 9; ++i)
            #pragma unroll
            for (int r = 0; r < 4; ++r) S[qt][i][r] = 0.f;

    #pragma unroll
    for (int i = 0; i < 9; ++i) {
        int mtk = wave * 9 + i;
        #pragma unroll
        for (int kk = 0; kk < 4; ++kk) {
            v8s b = *(const v8s*)(Kp + ((size_t)(mtk * 4 + kk)) * 512 + lane * 8);
            S[0][i] = __builtin_amdgcn_mfma_f32_16x16x32_bf16(aq[0][kk], b, S[0][i], 0, 0, 0);
            S[1][i] = __builtin_amdgcn_mfma_f32_16x16x32_bf16(aq[1][kk], b, S[1][i], 0, 0, 0);
        }
    }

    #pragma unroll
    for (int qt = 0; qt < 2; ++qt) {
        #pragma unroll
        for (int r = 0; r < 4; ++r) {
            float m = S[qt][0][r];
            #pragma unroll
            for (int i = 1; i < 9; ++i) m = fmaxf(m, S[qt][i][r]);
            #pragma unroll
            for (int off = 1; off < 16; off <<= 1) m = fmaxf(m, __shfl_xor(m, off));
            if (l15 == 0) redmx[wave][qt * 16 + q * 4 + r] = m;
        }
    }
    __syncthreads();
    float sum[2][4];
    #pragma unroll
    for (int qt = 0; qt < 2; ++qt) {
        #pragma unroll
        for (int r = 0; r < 4; ++r) {
            int rr = qt * 16 + q * 4 + r;
            float g = fmaxf(fmaxf(redmx[0][rr], redmx[1][rr]),
                            fmaxf(redmx[2][rr], redmx[3][rr]));
            float s = 0.f;
            #pragma unroll
            for (int i = 0; i < 9; ++i) { float e = __expf(S[qt][i][r] - g); S[qt][i][r] = e; s += e; }
            #pragma unroll
            for (int off = 1; off < 16; off <<= 1) s += __shfl_xor(s, off);
            sum[qt][r] = s;
        }
    }
    if (l15 == 0) {
        #pragma unroll
        for (int qt = 0; qt < 2; ++qt)
            #pragma unroll
            for (int r = 0; r < 4; ++r) redsm[wave][qt * 16 + q * 4 + r] = sum[qt][r];
    }
    #pragma unroll
    for (int qt = 0; qt < 2; ++qt) {
        #pragma unroll
        for (int i = 0; i < 9; ++i) {
            int m = (wave * 9 + i) * 16 + l15;
            int cm = m >> 3, mo = m & 7;
            #pragma unroll
            for (int r = 0; r < 4; ++r) {
                int n = qt * 16 + q * 4 + r;
                P[n * 576 + ((cm ^ (n & 7)) << 3) + mo] = f2bf(S[qt][i][r]);
            }
        }
    }
    __syncthreads();
    float inv[2][4];
    #pragma unroll
    for (int qt = 0; qt < 2; ++qt)
        #pragma unroll
        for (int r = 0; r < 4; ++r) {
            int rr = qt * 16 + q * 4 + r;
            inv[qt][r] = 1.f / (redsm[0][rr] + redsm[1][rr] + redsm[2][rr] + redsm[3][rr]);
        }

    v4f o[2][2];
    #pragma unroll
    for (int qt = 0; qt < 2; ++qt)
        #pragma unroll
        for (int ct = 0; ct < 2; ++ct)
            #pragma unroll
            for (int r = 0; r < 4; ++r) o[qt][ct][r] = 0.f;

    for (int s = 0; s < 18; ++s) {
        int cm = s * 4 + q;
        v8s a0 = *(const v8s*)&P[l15 * 576 + ((cm ^ (l15 & 7)) << 3)];
        v8s a1 = *(const v8s*)&P[(16 + l15) * 576 + ((cm ^ (l15 & 7)) << 3)];
        #pragma unroll
        for (int ct = 0; ct < 2; ++ct) {
            int ctile = wave * 2 + ct;
            v8s b = *(const v8s*)(Vp + ((size_t)(ctile * 18 + s)) * 512 + lane * 8);
            o[0][ct] = __builtin_amdgcn_mfma_f32_16x16x32_bf16(a0, b, o[0][ct], 0, 0, 0);
            o[1][ct] = __builtin_amdgcn_mfma_f32_16x16x32_bf16(a1, b, o[1][ct], 0, 0, 0);
        }
    }

    if (intra) {
        float al = alpha[0];
        #pragma unroll
        for (int qt = 0; qt < 2; ++qt)
            #pragma unroll
            for (int ct = 0; ct < 2; ++ct) {
                int c = (wave * 2 + ct) * 16 + l15;
                size_t base = ((size_t)p * 128 + c) * 576 + n0 + qt * 16 + q * 4;
                #pragma unroll
                for (int r = 0; r < 4; ++r)
                    Of[base + r] = al * o[qt][ct][r] * inv[qt][r] + addsrc[base + r];
            }
    } else {
        #pragma unroll
        for (int ct = 0; ct < 2; ++ct) {
            int c = (wave * 2 + ct) * 16 + l15;
            float sums[9];
            #pragma unroll
            for (int k = 0; k < 9; ++k) sums[k] = 0.f;
            #pragma unroll
            for (int qt = 0; qt < 2; ++qt) {
                size_t base = ((size_t)pp * 128 + c) * 576 + n0 + qt * 16 + q * 4;
                #pragma unroll
                for (int r = 0; r < 4; ++r) {
                    unsigned short hb = f2bf(o[qt][ct][r] * inv[qt][r]);
                    Oh[base + r] = hb;
                    float v = bf2f(hb);
                    int px = n0 + qt * 16 + q * 4 + r;
                    int row = px / 24, col = px % 24;
                    sums[0] += v;
                    if (row == 0)  sums[1] += v;
                    if (row == 23) sums[2] += v;
                    if (col == 0)  sums[3] += v;
                    if (col == 23) sums[4] += v;
                    if (px == 0)   sums[5] += v;
                    if (px == 23)  sums[6] += v;
                    if (px == 552) sums[7] += v;
                    if (px == 575) sums[8] += v;
                }
            }
            #pragma unroll
            for (int k = 0; k < 9; ++k) {
                sums[k] += __shfl_xor(sums[k], 16);
                sums[k] += __shfl_xor(sums[k], 32);
            }
            if (q == 0) {
                float* wp = wpart + (((size_t)pp * 18 + mt2) * 9) * 128 + c;
                #pragma unroll
                for (int k = 0; k < 9; ++k) wp[k * 128] = sums[k];
            }
        }
    }
}

// gate: reduce per-mt2 partials (L2-resident), 8-way split dot via WgT (1024 thr:
// 8 groups x 128 co — R10: halves the serial dot chain again vs R9's 4-way, which
// measured -6.7us/iter; tiny-grid serial-dot kernels pay ~linearly per halving)
__global__ __launch_bounds__(1024) void g_kernel(
    const float* __restrict__ wpart, const float* __restrict__ WgT,
    const float* __restrict__ Wgb, float* __restrict__ g)
{
    __shared__ float sw[C_ * 9];
    __shared__ float swp[7][C_ * 9];
    __shared__ float acc2[1024];
    int pair = blockIdx.x; int t = threadIdx.x;
    int co = t & 127, grp = t >> 7;
    const float* base = wpart + (size_t)pair * 18 * 9 * 128 + co;
    float raw[9];
    #pragma unroll
    for (int k = 0; k < 9; ++k) raw[k] = 0.f;
    for (int mt = grp; mt < 18; mt += 8) {
        #pragma unroll
        for (int k = 0; k < 9; ++k) raw[k] += base[(mt * 9 + k) * 128];
    }
    if (grp > 0) {
        #pragma unroll
        for (int k = 0; k < 9; ++k) swp[grp - 1][co * 9 + k] = raw[k];
    }
    __syncthreads();
    if (grp == 0) {
        #pragma unroll
        for (int k = 0; k < 9; ++k) {
            float a = raw[k];
            #pragma unroll
            for (int w = 0; w < 7; ++w) a += swp[w][co * 9 + k];
            raw[k] = a;
        }
        float rowsub[3] = {raw[2], 0.f, raw[1]};
        float colsub[3] = {raw[4], 0.f, raw[3]};
        float corner[9] = {raw[8], 0.f, raw[7], 0.f, 0.f, 0.f, raw[6], 0.f, raw[5]};
        #pragma unroll
        for (int ky = 0; ky < 3; ++ky)
            #pragma unroll
            for (int kx = 0; kx < 3; ++kx)
                sw[co * 9 + ky * 3 + kx] = raw[0] - rowsub[ky] - colsub[kx] + corner[ky * 3 + kx];
    }
    __syncthreads();
    float acc = 0.f;
    const float* wg = WgT + (size_t)grp * 144 * 128 + co;
    const float* swh = sw + grp * 144;
    for (int i = 0; i < 144; ++i) acc += wg[(size_t)i * 128] * swh[i];
    acc2[t] = acc;
    __syncthreads();
    if (grp == 0) {
        float a = acc;
        #pragma unroll
        for (int w = 1; w < 8; ++w) a += acc2[t + w * 128];
        float m = a * (1.f / 576.f) + Wgb[co];
        g[pair * C_ + co] = 1.f / (1.f + __expf(-m));
    }
}

// ----------------------- fused msg compute + transpose-cast -> msgT16 [px][c]
__global__ __launch_bounds__(256) void msg_tc_kernel(
    const float* __restrict__ eii, const unsigned short* __restrict__ mji,
    const float* __restrict__ g, const float* __restrict__ bn_gamma,
    const float* __restrict__ bn_beta, const float* __restrict__ intra_w,
    const float* __restrict__ inter_w, unsigned short* __restrict__ msgT)
{
    __shared__ float tile[128][9];
    int img = blockIdx.y, px0 = blockIdx.x * 8, t = threadIdx.x;
    int s = img >> 1, b = img & 1;
    float iw = intra_w[0], ew = inter_w[0];
    #pragma unroll
    for (int i = 0; i < 4; ++i) {
        int e = i * 256 + t; int ci = e >> 3; int pxl = e & 7;
        int px = px0 + pxl;
        float scale = bn_gamma[ci] * rsqrtf(1.f + 1e-5f);
        float acc = 0.f;
        #pragma unroll
        for (int jj = 0; jj < 4; ++jj) {
            int pidx = (s * 4 + jj) * 2 + b;
            acc += g[pidx * C_ + ci] * bf2f(mji[((size_t)pidx * C_ + ci) * N_ + px]);
        }
        float inter = scale * acc + 4.f * bn_beta[ci];
        tile[ci][pxl] = iw * eii[((size_t)img * C_ + ci) * N_ + px] + ew * inter;
    }
    __syncthreads();
    #pragma unroll
    for (int i = 0; i < 4; ++i) {
        int e = i * 256 + t; int pxl = e >> 7; int ci = e & 127;
        msgT[((size_t)img * 576 + px0 + pxl) * 128 + ci] = f2bf(tile[ci][pxl]);
    }
}

// -------- fused GRU update + next-iter transpose/packs (hT [px][c], VF pack)
__global__ __launch_bounds__(256) void update_tc_kernel(
    const float* __restrict__ zrp, const float* __restrict__ zrb,
    const float* __restrict__ hhp, const float* __restrict__ ghb,
    const float* __restrict__ h, float* __restrict__ out,
    unsigned short* __restrict__ hTn, unsigned short* __restrict__ VFn, int last)
{
    const size_t ZP = (size_t)SB * C2 * N_;
    const size_t HP = (size_t)SB * C_ * N_;
    __shared__ float tile[128][9];
    int img = blockIdx.y, px0 = blockIdx.x * 8, t = threadIdx.x;
    #pragma unroll
    for (int i = 0; i < 4; ++i) {
        int e = i * 256 + t; int ci = e >> 3; int pxl = e & 7;
        int px = px0 + pxl;
        size_t zi = ((size_t)img * C2 + ci) * N_ + px;
        float za = zrb[ci];
        #pragma unroll
        for (int k = 0; k < ZRSPLIT; ++k) za += zrp[k * ZP + zi];
        float z = 1.f / (1.f + __expf(-za));
        size_t hi = ((size_t)img * C_ + ci) * N_ + px;
        float ha = ghb[ci];
        #pragma unroll
        for (int k = 0; k < 4; ++k) ha += hhp[k * HP + hi];
        float hh = tanhf(ha);
        float o = (2.f - z) * h[hi] + z * hh;
        out[hi] = o;
        tile[ci][pxl] = o;
        if (!last) {
            int ctile = ci >> 4, l15v = ci & 15;
            int sIdx = px >> 5, quadv = (px >> 3) & 3, j = px & 7;
            VFn[(((size_t)img * 8 + ctile) * 18 + sIdx) * 512 + (quadv * 16 + l15v) * 8 + j] = f2bf(o);
        }
    }
    if (!last) {
        __syncthreads();
        #pragma unroll
        for (int i = 0; i < 4; ++i) {
            int e = i * 256 + t; int pxl = e >> 7; int ci = e & 127;
            hTn[((size_t)img * 576 + px0 + pxl) * 128 + ci] = f2bf(tile[ci][pxl]);
        }
    }
}

// ------------------------------------------------------------------- launcher
extern "C" void kernel_launch(void* const* d_in, const int* in_sizes, int n_in,
                              void* d_out, int out_size, void* d_ws, size_t ws_size,
                              hipStream_t stream)
{
    const float* x      = (const float*)d_in[0];
    const float* Wf_w   = (const float*)d_in[1];
    const float* Wf_b   = (const float*)d_in[2];
    const float* Wh_w   = (const float*)d_in[3];
    const float* Wh_b   = (const float*)d_in[4];
    const float* Wl_w   = (const float*)d_in[5];
    const float* Wl_b   = (const float*)d_in[6];
    const float* alpha  = (const float*)d_in[7];
    const float* Wc     = (const float*)d_in[8];
    const float* Wg_w   = (const float*)d_in[9];
    const float* Wg_b   = (const float*)d_in[10];
    const float* bng    = (const float*)d_in[11];
    const float* bnb    = (const float*)d_in[12];
    const float* zr_w   = (const float*)d_in[13];
    const float* zr_b   = (const float*)d_in[14];
    const float* gh_w   = (const float*)d_in[15];
    const float* gh_b   = (const float*)d_in[16];
    const float* intraw = (const float*)d_in[17];
    const float* interw = (const float*)d_in[18];
    float* outp = (float*)d_out;

    float* f = (float*)d_ws;
    const size_t SZ = (size_t)SB * C_ * N_;
    float* hbuf  = f; f += SZ;
    float* eii   = f; f += SZ;
    float* zrp   = f; f += (size_t)ZRSPLIT * SB * C2 * N_;
    float* hhp   = f; f += 4 * SZ;
    float* wpart = f; f += (size_t)NPAIR * 18 * 9 * 128;
    float* gbuf  = f; f += (size_t)NPAIR * C_;
    float* WgT   = f; f += (size_t)128 * 1152;
    unsigned short* us = (unsigned short*)f;
    unsigned short* mji16  = us; us += (size_t)NPAIR * C_ * N_;
    unsigned short* hT16   = us; us += SZ;
    unsigned short* hc16   = us; us += SZ;           // VFi inter / rhbT16
    unsigned short* msgT16 = us; us += SZ;
    unsigned short* ftT    = us; us += SZ;           // Q intra
    unsigned short* KFa    = us; us += SZ;
    unsigned short* VFa    = us; us += SZ;
    unsigned short* Wp3    = us; us += (size_t)384 * 1152;
    unsigned short* Wpzr   = us; us += (size_t)256 * 6400;
    unsigned short* Wph    = us; us += (size_t)128 * 6400;
    unsigned short* Wcb    = us; us += (size_t)128 * 128;
    unsigned short* KFi    = us; us += SZ;

    unsigned short* VFi    = hc16;
    unsigned short* rhbT16 = hc16;

    // all weight packs + initial transpose/pack of x in ONE launch
    pack_all_kernel<<<NB_A3 + NB_A5ZR + NB_A5H + NB_WC + NB_WGT + NB_TC, 256, 0, stream>>>(
        Wf_w, Wh_w, Wl_w, Wp3, zr_w, Wpzr, gh_w, Wph, Wc, Wcb, Wg_w, WgT,
        x, hT16, VFi);

    const float* hcur = x;
    for (int it = 0; it < 3; ++it) {
        float* hout = (it == 2) ? outp : hbuf;

        conv3_yt_kernel<<<540, 256, 0, stream>>>(
            hT16, Wp3, Wf_b, Wh_b, Wl_b, ftT, KFa, VFa, Wcb, KFi);
        attn_merged<<<900, 256, 0, stream>>>(
            ftT, KFa, VFa, eii, hcur, alpha, hT16, KFi, VFi, mji16, wpart);
        g_kernel<<<NPAIR, 1024, 0, stream>>>(wpart, WgT, Wg_b, gbuf);
        msg_tc_kernel<<<dim3(72, SB), 256, 0, stream>>>(
            eii, mji16, gbuf, bng, bnb, intraw, interw, msgT16);
        conv_mfma<5, 2, 256, ZRSPLIT, 0><<<dim3(4 * ZRSPLIT, 3, SB), 256, 0, stream>>>(
            msgT16, hT16, Wpzr, 256, zrp, nullptr, nullptr, nullptr, nullptr, nullptr, nullptr);
        tc_kernel<<<dim3(72, SB), 256, 0, stream>>>(hcur, zrp, zr_b, rhbT16, nullptr);
        conv_mfma<5, 2, 256, 4, 0><<<dim3(8, 3, SB), 256, 0, stream>>>(
            msgT16, rhbT16, Wph, 128, hhp, nullptr, nullptr, nullptr, nullptr, nullptr, nullptr);
        update_tc_kernel<<<dim3(72, SB), 256, 0, stream>>>(
            zrp, zr_b, hhp, gh_b, hcur, hout, hT16, VFi, (it == 2) ? 1 : 0);
        hcur = hout;
    }
}